// Round 4
// baseline (4216.894 us; speedup 1.0000x reference)
//
#include <hip/hip_runtime.h>
#include <math.h>

#define BB 16
#define LL 48
#define HH 1024
#define NG4 4096      // 4*H
#define NG6 6144      // 6*H
#define K3H 3072      // 3*H
#define RANKH 128
#define MAXN 47       // max nodes per batch (len-1 <= 47)
#define TOTN (BB*MAXN)
#define MAXLVL 48
#define MAXNPL 384    // max nodes in one level

#define CH 20         // padded floats per 16-float k-chunk in scan LDS
#define HROW (64*CH)  // 1280 floats per m-row

typedef __attribute__((ext_vector_type(8))) short bf16x8;
typedef __attribute__((ext_vector_type(4))) float f32x4;

__device__ __forceinline__ float sigf(float x){ return 1.f/(1.f + expf(-x)); }

__device__ __forceinline__ unsigned short f2bf(float f){
  union { float f; unsigned u; } v; v.f = f;
  unsigned r = v.u + 0x7fff + ((v.u >> 16) & 1);
  return (unsigned short)(r >> 16);
}

// Grid-wide barrier: monotone counter, agent-scope atomics + full fences
// (per-XCD L2 non-coherence requires the wb/inv that agent fences emit).
// COUNTER MUST BE ZEROED EVERY LAUNCH (workspace is re-poisoned to 0xAA).
__device__ __forceinline__ void gridbar(unsigned* bar, unsigned target){
  __syncthreads();
  if (threadIdx.x == 0){
    __threadfence();
    __hip_atomic_fetch_add(bar, 1u, __ATOMIC_RELEASE, __HIP_MEMORY_SCOPE_AGENT);
    while (__hip_atomic_load(bar, __ATOMIC_ACQUIRE, __HIP_MEMORY_SCOPE_AGENT) < target)
      __builtin_amdgcn_s_sleep(1);
    __threadfence();
  }
  __syncthreads();
}

// ---------------------------------------------------------------------------
// Zero ALL barrier counters used this launch: [0] = scan, [8] = tree.
__global__ __launch_bounds__(64) void k_init(unsigned* bar){
  if (threadIdx.x < 16) bar[threadIdx.x] = 0u;
}

// ---------------------------------------------------------------------------
// fp32 -> bf16 (RNE), vectorized. n multiple of 1024.
__global__ __launch_bounds__(256) void k_cvt_bf16(const float* __restrict__ in,
    unsigned short* __restrict__ out, int n){
  int i = (blockIdx.x*256 + threadIdx.x)*4;
  if (i >= n) return;
  float4 v = *(const float4*)(in + i);
  ushort4 o;
  o.x = f2bf(v.x); o.y = f2bf(v.y); o.z = f2bf(v.z); o.w = f2bf(v.w);
  *(ushort4*)(out + i) = o;
}

// ---------------------------------------------------------------------------
// Generic 32x32 LDS-tiled transpose: out[C][R] = in[R][C]^T  (R1 only now)
__global__ __launch_bounds__(256) void k_transpose(const float* __restrict__ in,
                                                   float* __restrict__ out, int R, int C){
  __shared__ float t[32][33];
  int bx = blockIdx.x*32, by = blockIdx.y*32;
  int x = threadIdx.x, y = threadIdx.y;   // block (32,8)
  #pragma unroll
  for (int i = 0; i < 32; i += 8){
    int r = by + y + i, c = bx + x;
    if (r < R && c < C) t[y+i][x] = in[(size_t)r*C + c];
  }
  __syncthreads();
  #pragma unroll
  for (int i = 0; i < 32; i += 8){
    int r = bx + y + i, c = by + x;       // out dims [C][R]
    if (r < C && c < R) out[(size_t)r*R + c] = t[x][y+i];
  }
}

// ---------------------------------------------------------------------------
// Gx[m][n] = sum_k se[m][k]*Wih[n][k] + bih[n] + bhh[n]   (fp32 — decision path)
__global__ __launch_bounds__(256) void k_gemm_gx(const float* __restrict__ A,
    const float* __restrict__ Bw, const float* __restrict__ bih,
    const float* __restrict__ bhh, float* __restrict__ Cout, int M, int N, int K){
  __shared__ float as[16][68];
  __shared__ float bs[16][68];
  int m0 = blockIdx.x*64, n0 = blockIdx.y*64;
  int tid = threadIdx.x;
  int mt = tid & 15, nt = tid >> 4;
  float acc[4][4] = {};
  for (int k0 = 0; k0 < K; k0 += 16){
    #pragma unroll
    for (int it = 0; it < 4; ++it){
      int idx = it*256 + tid;
      int kk = idx & 15, mm = idx >> 4;
      as[kk][mm] = A[(size_t)(m0+mm)*K + k0 + kk];
      bs[kk][mm] = Bw[(size_t)(n0+mm)*K + k0 + kk];
    }
    __syncthreads();
    #pragma unroll
    for (int kk = 0; kk < 16; ++kk){
      float a4[4], b4[4];
      #pragma unroll
      for (int i = 0; i < 4; ++i) a4[i] = as[kk][mt*4+i];
      #pragma unroll
      for (int i = 0; i < 4; ++i) b4[i] = bs[kk][nt*4+i];
      #pragma unroll
      for (int i = 0; i < 4; ++i)
        #pragma unroll
        for (int j2 = 0; j2 < 4; ++j2) acc[i][j2] += a4[i]*b4[j2];
    }
    __syncthreads();
  }
  #pragma unroll
  for (int i = 0; i < 4; ++i){
    int m = m0 + mt*4 + i;
    #pragma unroll
    for (int j2 = 0; j2 < 4; ++j2){
      int n = n0 + nt*4 + j2;
      Cout[(size_t)m*N + n] = acc[i][j2] + bih[n] + bhh[n];
    }
  }
}

// ---------------------------------------------------------------------------
// Gx [m][t][4096] -> Gxt [t][4096][m]  (for coalesced per-step gate reads)
__global__ __launch_bounds__(256) void k_gx_t(const float* __restrict__ Gx,
                                              float* __restrict__ Gxt){
  __shared__ float t2[16][257];
  int t = blockIdx.x;       // 48
  int rc = blockIdx.y;      // 16 chunks of 256 rows
  int tid = threadIdx.x;
  #pragma unroll
  for (int m = 0; m < 16; ++m)
    t2[m][tid] = Gx[((size_t)(m*48 + t))*4096 + rc*256 + tid];
  __syncthreads();
  int rl = tid >> 4, m = tid & 15;
  #pragma unroll
  for (int i = 0; i < 16; ++i){
    int r = rc*256 + i*16 + rl;
    Gxt[((size_t)t*4096 + r)*16 + m] = t2[m][i*16 + rl];
  }
}

// ---------------------------------------------------------------------------
// Persistent LSTM scan: 256 blocks x 256 threads, 1 block/CU.
// Block cb owns j in {4cb..4cb+3}; wave g handles gate g (rows g*1024+j0+jj).
// Whh held in registers (w[4][16] per lane, lane=k-chunk of 16).
__global__ __launch_bounds__(256, 1) void k_lstm_scan(
    const float* __restrict__ Whh, const float* __restrict__ Gxt,
    float* __restrict__ hs, float* __restrict__ cs,
    unsigned short* __restrict__ hs_bf, unsigned* __restrict__ bar){
  __shared__ float smem[16*HROW];   // 80KB: h-stage; overlaid by reduce partials
  __shared__ float gbuf[4*64];
  __shared__ float cbuf[64];
  int tid = threadIdx.x;
  int g = tid >> 6, kc = tid & 63;
  int j0 = blockIdx.x * 4;
  // preload weights
  float w[4][16];
  #pragma unroll
  for (int jj = 0; jj < 4; ++jj){
    const float* src = Whh + (size_t)(g*1024 + j0 + jj)*1024 + kc*16;
    #pragma unroll
    for (int kk = 0; kk < 16; kk += 4){
      float4 v = *(const float4*)(src + kk);
      w[jj][kk]=v.x; w[jj][kk+1]=v.y; w[jj][kk+2]=v.z; w[jj][kk+3]=v.w;
    }
  }
  if (tid < 64) cbuf[tid] = 0.f;
  unsigned target = 0;
  for (int t = 0; t < LL; ++t){
    float G = 0.f;
    if (t > 0){
      // stage h_{t-1} into LDS (padded chunk layout to avoid bank conflicts)
      #pragma unroll
      for (int m = 0; m < 16; ++m){
        float4 v = *(const float4*)(hs + ((size_t)(m*LL + t-1))*HH + (tid<<2));
        *(float4*)&smem[m*HROW + (tid>>2)*CH + (tid&3)*4] = v;
      }
      __syncthreads();
      // GEMV: acc[jj][m] = sum over this lane's 16-k slice
      float acc[4][16];
      #pragma unroll 4
      for (int m = 0; m < 16; ++m){
        const float* hb = &smem[m*HROW + kc*CH];
        float4 h0 = *(const float4*)(hb);
        float4 h1 = *(const float4*)(hb+4);
        float4 h2 = *(const float4*)(hb+8);
        float4 h3 = *(const float4*)(hb+12);
        #pragma unroll
        for (int jj = 0; jj < 4; ++jj){
          float s = w[jj][0]*h0.x + w[jj][1]*h0.y + w[jj][2]*h0.z + w[jj][3]*h0.w
                  + w[jj][4]*h1.x + w[jj][5]*h1.y + w[jj][6]*h1.z + w[jj][7]*h1.w
                  + w[jj][8]*h2.x + w[jj][9]*h2.y + w[jj][10]*h2.z + w[jj][11]*h2.w
                  + w[jj][12]*h3.x + w[jj][13]*h3.y + w[jj][14]*h3.z + w[jj][15]*h3.w;
          acc[jj][m] = s;
        }
      }
      __syncthreads();   // hsm reads done; smem now reused as reduce partials
      // write partials: red[g][kc][pos], pos = m*4+jj  (row stride 68 floats)
      #pragma unroll
      for (int m = 0; m < 16; ++m){
        float4 v;
        v.x = acc[0][m]; v.y = acc[1][m]; v.z = acc[2][m]; v.w = acc[3][m];
        *(float4*)&smem[(size_t)(g*64 + kc)*68 + m*4] = v;
      }
      __syncthreads();
      // gather: lane o=kc sums its position over 64 source lanes
      {
        float s0=0.f,s1=0.f,s2=0.f,s3=0.f;
        #pragma unroll 4
        for (int l = 0; l < 64; l += 4){
          s0 += smem[(size_t)(g*64 + l  )*68 + kc];
          s1 += smem[(size_t)(g*64 + l+1)*68 + kc];
          s2 += smem[(size_t)(g*64 + l+2)*68 + kc];
          s3 += smem[(size_t)(g*64 + l+3)*68 + kc];
        }
        G = (s0+s1)+(s2+s3);
      }
    }
    gbuf[g*64 + kc] = G;
    __syncthreads();
    if (g == 0){
      int o = kc;               // o = m*4 + jj
      int jj = o & 3, m = o >> 2;
      size_t gxb = ((size_t)t*NG4 + j0 + jj)*16 + m;
      float gi = gbuf[0*64 + o] + Gxt[gxb + 0*16384];
      float gf = gbuf[1*64 + o] + Gxt[gxb + 1*16384];
      float gu = gbuf[2*64 + o] + Gxt[gxb + 2*16384];
      float go = gbuf[3*64 + o] + Gxt[gxb + 3*16384];
      float cp = cbuf[o];
      float c = sigf(gf)*cp + sigf(gi)*tanhf(gu);
      float h = sigf(go)*tanhf(c);
      cbuf[o] = c;
      size_t oidx = ((size_t)(m*LL + t))*HH + j0 + jj;
      hs[oidx] = h;
      cs[oidx] = c;
      hs_bf[oidx] = f2bf(h);
    }
    target += 256;
    gridbar(bar, target);
  }
}

// ---------------------------------------------------------------------------
// Per-position rank-MLP score + gumbel noise (fp32 — decision path).
__global__ __launch_bounds__(128) void k_score(const float* __restrict__ R1t,
    const float* __restrict__ R2, const float* __restrict__ hs,
    const float* __restrict__ gumbel_u, float* __restrict__ score,
    float* __restrict__ snoisy){
  __shared__ float hsm[HH];
  __shared__ float red[128];
  int bt = blockIdx.x;
  int tid = threadIdx.x;
  for (int i = tid; i < HH; i += 128) hsm[i] = hs[(size_t)bt*HH + i];
  __syncthreads();
  float acc = 0.f;
  for (int k = 0; k < HH; ++k) acc += R1t[(size_t)k*RANKH + tid] * hsm[k];
  red[tid] = fmaxf(acc, 0.f) * R2[tid];
  __syncthreads();
  for (int s = 64; s > 0; s >>= 1){
    if (tid < s) red[tid] += red[tid+s];
    __syncthreads();
  }
  if (tid == 0){
    float s = red[0];
    float u = gumbel_u[bt];
    float noise = -logf(-logf(u));
    score[bt]  = s;
    snoisy[bt] = s + noise;
  }
}

// ---------------------------------------------------------------------------
// Build the tree structure for all batches. 1 block, 64 threads.
// level_count[0] <- number of levels (max height).
__global__ __launch_bounds__(64) void k_build(const float* __restrict__ score,
    const float* __restrict__ snoisy, const int* __restrict__ length,
    int* __restrict__ node_l, int* __restrict__ node_r, int* __restrict__ node_x,
    int* __restrict__ node_lvl, int* __restrict__ node_b, int* __restrict__ node_root,
    int* __restrict__ level_count, int* __restrict__ level_off, int* __restrict__ order){
  __shared__ float sc[BB*LL], sn[BB*LL];
  __shared__ int lcount[MAXLVL+1], lcur[MAXLVL+1], loff[MAXLVL+1];
  __shared__ int percnt[BB];
  int tid = threadIdx.x;
  for (int i = tid; i < BB*LL; i += 64){ sc[i] = score[i]; sn[i] = snoisy[i]; }
  for (int i = tid; i <= MAXLVL; i += 64){ lcount[i] = 0; lcur[i] = 0; }
  __syncthreads();
  if (tid < BB){
    int b = tid;
    int len = length[b];
    if (len > LL) len = LL;
    int qs[MAXN], qe[MAXN], qn[MAXN];
    int qh = 0, qt = 0, cnt = 0;
    int rootn = cnt++;
    qs[qt] = 0; qe[qt] = len; qn[qt] = rootn; qt++;
    while (qh < qt){
      int s0 = qs[qh], e0 = qe[qh], nid = qn[qh]; qh++;
      float best = sc[b*LL + s0]; int pos = s0;
      for (int t2 = s0+1; t2 < e0; ++t2){
        float v = sc[b*LL + t2];
        if (v > best){ best = v; pos = t2; }
      }
      float bestn = sn[b*LL + s0]; int js = s0;
      for (int t2 = s0+1; t2 < e0; ++t2){
        float v = sn[b*LL + t2];
        if (v > bestn){ bestn = v; js = t2; }
      }
      int gid = b*MAXN + nid;
      node_x[gid] = js;
      node_b[gid] = b;
      node_root[gid] = (nid == 0) ? 1 : 0;
      int ln = pos - s0, enc_l, enc_r;
      if (ln <= 0) enc_l = -1;
      else if (ln == 1) enc_l = 10000 + s0;
      else { int c2 = cnt++; enc_l = b*MAXN + c2; qs[qt]=s0; qe[qt]=pos; qn[qt]=c2; qt++; }
      int rn = e0 - (pos+1);
      if (rn <= 0) enc_r = -1;
      else if (rn == 1) enc_r = 10000 + (pos+1);
      else { int c2 = cnt++; enc_r = b*MAXN + c2; qs[qt]=pos+1; qe[qt]=e0; qn[qt]=c2; qt++; }
      node_l[gid] = enc_l; node_r[gid] = enc_r;
    }
    for (int i = cnt-1; i >= 0; --i){
      int gid = b*MAXN + i;
      int el = node_l[gid], er = node_r[gid];
      int llv = (el >= 0 && el < 10000) ? node_lvl[el] : 0;
      int rlv = (er >= 0 && er < 10000) ? node_lvl[er] : 0;
      node_lvl[gid] = 1 + (llv > rlv ? llv : rlv);
    }
    for (int i = 0; i < cnt; ++i) atomicAdd(&lcount[node_lvl[b*MAXN + i]], 1);
    percnt[b] = cnt;
  }
  __syncthreads();
  if (tid == 0){
    int off = 0, nlev = 0;
    for (int lv = 1; lv <= MAXLVL; ++lv){
      loff[lv] = off;
      level_off[lv] = off;
      level_count[lv] = lcount[lv];
      if (lcount[lv] > 0) nlev = lv;
      off += lcount[lv];
    }
    level_count[0] = nlev;
  }
  __syncthreads();
  if (tid < BB){
    int b = tid;
    int cnt = percnt[b];
    for (int i = 0; i < cnt; ++i){
      int gid = b*MAXN + i;
      int lv = node_lvl[gid];
      int p = atomicAdd(&lcur[lv], 1);
      order[loff[lv] + p] = gid;
    }
  }
}

// ---------------------------------------------------------------------------
// Persistent tree-composition kernel: loops levels internally with grid
// barriers. Phase A: bf16 MFMA GEMM tiles (64 nodes x 64 Wc rows x K=3072).
// Phase B: bias + nary tree-LSTM cell epilogue.
__global__ __launch_bounds__(256, 1) void k_tree(
    const unsigned short* __restrict__ Wc_bf,
    const unsigned short* __restrict__ hs_bf,
    unsigned short* __restrict__ nodeH_bf,
    const float* __restrict__ bc, const float* __restrict__ cs,
    float* __restrict__ nodeC,
    const int* __restrict__ node_l, const int* __restrict__ node_r,
    const int* __restrict__ node_x, const int* __restrict__ node_b,
    const int* __restrict__ node_root, const int* __restrict__ level_count,
    const int* __restrict__ level_off, const int* __restrict__ order,
    float* __restrict__ gates, float* __restrict__ out,
    unsigned* __restrict__ bar){
  __shared__ unsigned short As[64][40];
  __shared__ unsigned short Bs[64][40];
  __shared__ const unsigned short* srcp[64][3];
  int tid = threadIdx.x;
  int lane = tid & 63;
  int wave = tid >> 6;
  int wm = wave >> 1, wn = wave & 1;
  int nlev = level_count[0];
  unsigned target = 0;
  for (int lvl = 1; lvl <= nlev; ++lvl){
    int n = level_count[lvl];
    int loffv = level_off[lvl];
    int ntg = (n + 63) >> 6;
    int tiles = ntg * 96;
    // ---- Phase A: GEMM tiles ----
    for (int tile = blockIdx.x; tile < tiles; tile += 256){
      int ng = tile / 96, rg = tile - ng*96;
      __syncthreads();
      if (tid < 64){
        const unsigned short *p0 = nullptr, *p1 = nullptr, *p2 = nullptr;
        if (ng*64 + tid < n){
          int gid = order[loffv + ng*64 + tid];
          int b = node_b[gid];
          int el = node_l[gid], er = node_r[gid], xt = node_x[gid];
          p0 = (el < 0) ? nullptr : (el >= 10000 ? hs_bf + (size_t)(b*LL + (el-10000))*HH
                                                 : nodeH_bf + (size_t)el*HH);
          p1 = (er < 0) ? nullptr : (er >= 10000 ? hs_bf + (size_t)(b*LL + (er-10000))*HH
                                                 : nodeH_bf + (size_t)er*HH);
          p2 = hs_bf + (size_t)(b*LL + xt)*HH;
        }
        srcp[tid][0] = p0; srcp[tid][1] = p1; srcp[tid][2] = p2;
      }
      __syncthreads();
      f32x4 acc[2][2] = {{{0.f,0.f,0.f,0.f},{0.f,0.f,0.f,0.f}},
                         {{0.f,0.f,0.f,0.f},{0.f,0.f,0.f,0.f}}};
      int arow = tid >> 2;
      int koff = (tid & 3) * 8;
      const unsigned short* Brow = Wc_bf + (size_t)(rg*64 + arow)*K3H + koff;
      int fr = lane & 15, fk = (lane >> 4) * 8;
      for (int part = 0; part < 3; ++part){
        const unsigned short* p = srcp[arow][part];
        for (int kcc = 0; kcc < 1024; kcc += 32){
          uint4 av = p ? *(const uint4*)(p + kcc + koff) : make_uint4(0u,0u,0u,0u);
          uint4 bv = *(const uint4*)(Brow + part*1024 + kcc);
          __syncthreads();
          *(uint4*)&As[arow][koff] = av;
          *(uint4*)&Bs[arow][koff] = bv;
          __syncthreads();
          bf16x8 a0 = *(bf16x8*)&As[wm*32 +      fr][fk];
          bf16x8 a1 = *(bf16x8*)&As[wm*32 + 16 + fr][fk];
          bf16x8 b0 = *(bf16x8*)&Bs[wn*32 +      fr][fk];
          bf16x8 b1 = *(bf16x8*)&Bs[wn*32 + 16 + fr][fk];
          acc[0][0] = __builtin_amdgcn_mfma_f32_16x16x32_bf16(a0, b0, acc[0][0], 0, 0, 0);
          acc[0][1] = __builtin_amdgcn_mfma_f32_16x16x32_bf16(a0, b1, acc[0][1], 0, 0, 0);
          acc[1][0] = __builtin_amdgcn_mfma_f32_16x16x32_bf16(a1, b0, acc[1][0], 0, 0, 0);
          acc[1][1] = __builtin_amdgcn_mfma_f32_16x16x32_bf16(a1, b1, acc[1][1], 0, 0, 0);
        }
      }
      int crow4 = (lane >> 4)*4, ccol = lane & 15;
      #pragma unroll
      for (int ti = 0; ti < 2; ++ti)
        #pragma unroll
        for (int tj = 0; tj < 2; ++tj)
          #pragma unroll
          for (int r = 0; r < 4; ++r){
            int m = wm*32 + ti*16 + crow4 + r;
            int nn = wn*32 + tj*16 + ccol;
            gates[(size_t)(ng*64 + m)*NG6 + rg*64 + nn] = acc[ti][tj][r];
          }
    }
    target += 256;
    gridbar(bar, target);
    // ---- Phase B: epilogue ----
    int items = n * 4;
    for (int it = blockIdx.x; it < items; it += 256){
      int ns = it >> 2;
      int j = (it & 3)*256 + tid;
      int gid = order[loffv + ns];
      int b = node_b[gid];
      int el = node_l[gid], er = node_r[gid], xt = node_x[gid];
      float gg[6];
      #pragma unroll
      for (int q = 0; q < 6; ++q)
        gg[q] = bc[q*HH + j] + gates[(size_t)ns*NG6 + q*HH + j];
      float lc = (el < 0) ? 0.f : (el >= 10000 ? cs[(size_t)(b*LL + (el-10000))*HH + j]
                                               : nodeC[(size_t)el*HH + j]);
      float rc = (er < 0) ? 0.f : (er >= 10000 ? cs[(size_t)(b*LL + (er-10000))*HH + j]
                                               : nodeC[(size_t)er*HH + j]);
      float xc = cs[(size_t)(b*LL + xt)*HH + j];
      float c = sigf(gg[0])*tanhf(gg[4]) + sigf(gg[1])*lc + sigf(gg[2])*rc + sigf(gg[3])*xc;
      float h = sigf(gg[5])*tanhf(c);
      nodeH_bf[(size_t)gid*HH + j] = f2bf(h);
      nodeC[(size_t)gid*HH + j] = c;
      if (node_root[gid]){
        out[(size_t)b*HH + j] = h;
        out[(size_t)BB*HH + (size_t)b*HH + j] = c;
      }
    }
    target += 256;
    gridbar(bar, target);
  }
}

// ---------------------------------------------------------------------------
extern "C" void kernel_launch(void* const* d_in, const int* in_sizes, int n_in,
                              void* d_out, int out_size, void* d_ws, size_t ws_size,
                              hipStream_t stream){
  const float* se  = (const float*)d_in[0];
  const float* gu  = (const float*)d_in[1];
  const float* Wih = (const float*)d_in[2];
  const float* Whh = (const float*)d_in[3];
  const float* bih = (const float*)d_in[4];
  const float* bhh = (const float*)d_in[5];
  const float* R1  = (const float*)d_in[6];
  const float* R2  = (const float*)d_in[7];
  const float* Wc  = (const float*)d_in[8];
  const float* bc  = (const float*)d_in[9];
  const int*   len = (const int*)d_in[10];
  float* out = (float*)d_out;                 // [2,16,1024] fp32

  float* ws = (float*)d_ws;
  size_t off = 0;
  float* R1t   = ws + off; off += (size_t)HH*RANKH;      // R1^T fp32
  float* Gx    = ws + off; off += (size_t)BB*LL*NG4;     // input gates [m][t][4096]
  float* Gxt   = ws + off; off += (size_t)BB*LL*NG4;     // [t][4096][m]
  float* hs    = ws + off; off += (size_t)BB*LL*HH;      // fp32 (decision path)
  float* cs    = ws + off; off += (size_t)BB*LL*HH;      // fp32
  float* nodeC = ws + off; off += (size_t)TOTN*HH;       // fp32
  float* gates = ws + off; off += (size_t)MAXNPL*NG6;    // fp32 level gates
  unsigned short* Wc_bf    = (unsigned short*)(ws + off); off += (size_t)NG6*K3H/2;
  unsigned short* hs_bf    = (unsigned short*)(ws + off); off += (size_t)BB*LL*HH/2;
  unsigned short* nodeH_bf = (unsigned short*)(ws + off); off += (size_t)TOTN*HH/2 + 512;
  float* score = ws + off; off += 1024;
  float* snoi  = ws + off; off += 1024;
  unsigned* bar = (unsigned*)(ws + off); off += 64;
  int* ib = (int*)(ws + off);
  int* node_l    = ib; ib += 768;
  int* node_r    = ib; ib += 768;
  int* node_x    = ib; ib += 768;
  int* node_lvl  = ib; ib += 768;
  int* node_b    = ib; ib += 768;
  int* node_root = ib; ib += 768;
  int* level_count = ib; ib += 64;
  int* level_off   = ib; ib += 64;
  int* order       = ib; ib += 768;

  // 0. zero grid-barrier counters ([0]=scan, [8]=tree; ws poisoned every launch)
  k_init<<<1, 64, 0, stream>>>(bar);
  // 1. R1 transpose + Wc bf16 conversion
  k_transpose<<<dim3(32, 4), dim3(32, 8), 0, stream>>>(R1, R1t, RANKH, HH);
  k_cvt_bf16<<<(NG6*K3H)/1024, 256, 0, stream>>>(Wc, Wc_bf, NG6*K3H);
  // 2. input-side gate GEMM (+ both biases), then transpose for the scan
  k_gemm_gx<<<dim3(12, 64), 256, 0, stream>>>(se, Wih, bih, bhh, Gx, BB*LL, NG4, HH);
  k_gx_t<<<dim3(48, 16), 256, 0, stream>>>(Gx, Gxt);
  // 3. persistent recurrent LSTM scan (48 steps, grid barriers)
  k_lstm_scan<<<256, 256, 0, stream>>>(Whh, Gxt, hs, cs, hs_bf, bar);
  // 4. per-position scores + gumbel noise (fp32)
  k_score<<<BB*LL, 128, 0, stream>>>(R1t, R2, hs, gu, score, snoi);
  // 5. tree structure
  k_build<<<1, 64, 0, stream>>>(score, snoi, len, node_l, node_r, node_x,
                                node_lvl, node_b, node_root,
                                level_count, level_off, order);
  // 6. persistent level-by-level nary composition
  k_tree<<<256, 256, 0, stream>>>(Wc_bf, hs_bf, nodeH_bf, bc, cs, nodeC,
                                  node_l, node_r, node_x, node_b, node_root,
                                  level_count, level_off, order,
                                  gates, out, bar + 8);
}

// Round 5
// 2658.996 us; speedup vs baseline: 1.5859x; 1.5859x over previous
//
#include <hip/hip_runtime.h>
#include <math.h>

#define BB 16
#define LL 48
#define HH 1024
#define NG4 4096      // 4*H
#define NG6 6144      // 6*H
#define K3H 3072      // 3*H
#define RANKH 128
#define MAXN 47       // max nodes per batch (len-1 <= 47)
#define TOTN (BB*MAXN)
#define MAXLVL 48
#define MAXNPL 384    // max nodes in one level

#define CH 20         // padded floats per 16-float k-chunk in scan LDS
#define HROW (64*CH)  // 1280 floats per m-row

typedef __attribute__((ext_vector_type(8))) short bf16x8;
typedef __attribute__((ext_vector_type(4))) float f32x4;

__device__ __forceinline__ float sigf(float x){ return 1.f/(1.f + expf(-x)); }

__device__ __forceinline__ unsigned short f2bf(float f){
  union { float f; unsigned u; } v; v.f = f;
  unsigned r = v.u + 0x7fff + ((v.u >> 16) & 1);
  return (unsigned short)(r >> 16);
}

// Grid-wide barrier. Spin uses RELAXED agent loads (no per-poll cache
// invalidate); exactly ONE acquire load after the spin, release on the add.
// COUNTER MUST BE ZEROED EVERY LAUNCH (workspace is re-poisoned to 0xAA).
__device__ __forceinline__ void gridbar(unsigned* bar, unsigned target){
  __syncthreads();
  if (threadIdx.x == 0){
    __hip_atomic_fetch_add(bar, 1u, __ATOMIC_RELEASE, __HIP_MEMORY_SCOPE_AGENT);
    while (__hip_atomic_load(bar, __ATOMIC_RELAXED, __HIP_MEMORY_SCOPE_AGENT) < target)
      __builtin_amdgcn_s_sleep(2);
    (void)__hip_atomic_load(bar, __ATOMIC_ACQUIRE, __HIP_MEMORY_SCOPE_AGENT);
  }
  __syncthreads();
}

// ---------------------------------------------------------------------------
// Zero barrier counters ([0]=scan, [8]=tree) + the zero dummy row.
__global__ __launch_bounds__(256) void k_init(unsigned* bar, unsigned short* zrow){
  int tid = threadIdx.x;
  if (tid < 16) bar[tid] = 0u;
  for (int i = tid; i < 1024; i += 256) zrow[i] = 0;
}

// ---------------------------------------------------------------------------
// fp32 -> bf16 (RNE), vectorized. n multiple of 1024.
__global__ __launch_bounds__(256) void k_cvt_bf16(const float* __restrict__ in,
    unsigned short* __restrict__ out, int n){
  int i = (blockIdx.x*256 + threadIdx.x)*4;
  if (i >= n) return;
  float4 v = *(const float4*)(in + i);
  ushort4 o;
  o.x = f2bf(v.x); o.y = f2bf(v.y); o.z = f2bf(v.z); o.w = f2bf(v.w);
  *(ushort4*)(out + i) = o;
}

// ---------------------------------------------------------------------------
// Generic 32x32 LDS-tiled transpose: out[C][R] = in[R][C]^T  (R1 only)
__global__ __launch_bounds__(256) void k_transpose(const float* __restrict__ in,
                                                   float* __restrict__ out, int R, int C){
  __shared__ float t[32][33];
  int bx = blockIdx.x*32, by = blockIdx.y*32;
  int x = threadIdx.x, y = threadIdx.y;   // block (32,8)
  #pragma unroll
  for (int i = 0; i < 32; i += 8){
    int r = by + y + i, c = bx + x;
    if (r < R && c < C) t[y+i][x] = in[(size_t)r*C + c];
  }
  __syncthreads();
  #pragma unroll
  for (int i = 0; i < 32; i += 8){
    int r = bx + y + i, c = by + x;       // out dims [C][R]
    if (r < C && c < R) out[(size_t)r*R + c] = t[x][y+i];
  }
}

// ---------------------------------------------------------------------------
// Gx[m][n] = sum_k se[m][k]*Wih[n][k] + bih[n] + bhh[n]   (fp32 — decision path)
__global__ __launch_bounds__(256) void k_gemm_gx(const float* __restrict__ A,
    const float* __restrict__ Bw, const float* __restrict__ bih,
    const float* __restrict__ bhh, float* __restrict__ Cout, int M, int N, int K){
  __shared__ float as[16][68];
  __shared__ float bs[16][68];
  int m0 = blockIdx.x*64, n0 = blockIdx.y*64;
  int tid = threadIdx.x;
  int mt = tid & 15, nt = tid >> 4;
  float acc[4][4] = {};
  for (int k0 = 0; k0 < K; k0 += 16){
    #pragma unroll
    for (int it = 0; it < 4; ++it){
      int idx = it*256 + tid;
      int kk = idx & 15, mm = idx >> 4;
      as[kk][mm] = A[(size_t)(m0+mm)*K + k0 + kk];
      bs[kk][mm] = Bw[(size_t)(n0+mm)*K + k0 + kk];
    }
    __syncthreads();
    #pragma unroll
    for (int kk = 0; kk < 16; ++kk){
      float a4[4], b4[4];
      #pragma unroll
      for (int i = 0; i < 4; ++i) a4[i] = as[kk][mt*4+i];
      #pragma unroll
      for (int i = 0; i < 4; ++i) b4[i] = bs[kk][nt*4+i];
      #pragma unroll
      for (int i = 0; i < 4; ++i)
        #pragma unroll
        for (int j2 = 0; j2 < 4; ++j2) acc[i][j2] += a4[i]*b4[j2];
    }
    __syncthreads();
  }
  #pragma unroll
  for (int i = 0; i < 4; ++i){
    int m = m0 + mt*4 + i;
    #pragma unroll
    for (int j2 = 0; j2 < 4; ++j2){
      int n = n0 + nt*4 + j2;
      Cout[(size_t)m*N + n] = acc[i][j2] + bih[n] + bhh[n];
    }
  }
}

// ---------------------------------------------------------------------------
// Gx [m][t][4096] -> Gxt [t][4096][m]  (for coalesced per-step gate reads)
__global__ __launch_bounds__(256) void k_gx_t(const float* __restrict__ Gx,
                                              float* __restrict__ Gxt){
  __shared__ float t2[16][257];
  int t = blockIdx.x;       // 48
  int rc = blockIdx.y;      // 16 chunks of 256 rows
  int tid = threadIdx.x;
  #pragma unroll
  for (int m = 0; m < 16; ++m)
    t2[m][tid] = Gx[((size_t)(m*48 + t))*4096 + rc*256 + tid];
  __syncthreads();
  int rl = tid >> 4, m = tid & 15;
  #pragma unroll
  for (int i = 0; i < 16; ++i){
    int r = rc*256 + i*16 + rl;
    Gxt[((size_t)t*4096 + r)*16 + m] = t2[m][i*16 + rl];
  }
}

// ---------------------------------------------------------------------------
// Persistent LSTM scan: 256 blocks x 256 threads, 1 block/CU.
// Block cb owns j in {4cb..4cb+3}; wave g handles gate g.
// Whh held in registers (w[4][16] per lane, lane=k-chunk of 16).
__global__ __launch_bounds__(256, 1) void k_lstm_scan(
    const float* __restrict__ Whh, const float* __restrict__ Gxt,
    float* __restrict__ hs, float* __restrict__ cs,
    unsigned short* __restrict__ hs_bf, unsigned* __restrict__ bar){
  __shared__ float smem[16*HROW];   // 80KB: h-stage; overlaid by reduce partials
  __shared__ float gbuf[4*64];
  __shared__ float cbuf[64];
  int tid = threadIdx.x;
  int g = tid >> 6, kc = tid & 63;
  int j0 = blockIdx.x * 4;
  float w[4][16];
  #pragma unroll
  for (int jj = 0; jj < 4; ++jj){
    const float* src = Whh + (size_t)(g*1024 + j0 + jj)*1024 + kc*16;
    #pragma unroll
    for (int kk = 0; kk < 16; kk += 4){
      float4 v = *(const float4*)(src + kk);
      w[jj][kk]=v.x; w[jj][kk+1]=v.y; w[jj][kk+2]=v.z; w[jj][kk+3]=v.w;
    }
  }
  if (tid < 64) cbuf[tid] = 0.f;
  unsigned target = 0;
  for (int t = 0; t < LL; ++t){
    float G = 0.f;
    if (t > 0){
      #pragma unroll
      for (int m = 0; m < 16; ++m){
        float4 v = *(const float4*)(hs + ((size_t)(m*LL + t-1))*HH + (tid<<2));
        *(float4*)&smem[m*HROW + (tid>>2)*CH + (tid&3)*4] = v;
      }
      __syncthreads();
      float acc[4][16];
      #pragma unroll 4
      for (int m = 0; m < 16; ++m){
        const float* hb = &smem[m*HROW + kc*CH];
        float4 h0 = *(const float4*)(hb);
        float4 h1 = *(const float4*)(hb+4);
        float4 h2 = *(const float4*)(hb+8);
        float4 h3 = *(const float4*)(hb+12);
        #pragma unroll
        for (int jj = 0; jj < 4; ++jj){
          float s = w[jj][0]*h0.x + w[jj][1]*h0.y + w[jj][2]*h0.z + w[jj][3]*h0.w
                  + w[jj][4]*h1.x + w[jj][5]*h1.y + w[jj][6]*h1.z + w[jj][7]*h1.w
                  + w[jj][8]*h2.x + w[jj][9]*h2.y + w[jj][10]*h2.z + w[jj][11]*h2.w
                  + w[jj][12]*h3.x + w[jj][13]*h3.y + w[jj][14]*h3.z + w[jj][15]*h3.w;
          acc[jj][m] = s;
        }
      }
      __syncthreads();   // hsm reads done; smem reused as reduce partials
      #pragma unroll
      for (int m = 0; m < 16; ++m){
        float4 v;
        v.x = acc[0][m]; v.y = acc[1][m]; v.z = acc[2][m]; v.w = acc[3][m];
        *(float4*)&smem[(size_t)(g*64 + kc)*68 + m*4] = v;
      }
      __syncthreads();
      {
        float s0=0.f,s1=0.f,s2=0.f,s3=0.f;
        #pragma unroll 4
        for (int l = 0; l < 64; l += 4){
          s0 += smem[(size_t)(g*64 + l  )*68 + kc];
          s1 += smem[(size_t)(g*64 + l+1)*68 + kc];
          s2 += smem[(size_t)(g*64 + l+2)*68 + kc];
          s3 += smem[(size_t)(g*64 + l+3)*68 + kc];
        }
        G = (s0+s1)+(s2+s3);
      }
    }
    gbuf[g*64 + kc] = G;
    __syncthreads();
    if (g == 0){
      int o = kc;               // o = m*4 + jj
      int jj = o & 3, m = o >> 2;
      size_t gxb = ((size_t)t*NG4 + j0 + jj)*16 + m;
      float gi = gbuf[0*64 + o] + Gxt[gxb + 0*16384];
      float gf = gbuf[1*64 + o] + Gxt[gxb + 1*16384];
      float gu = gbuf[2*64 + o] + Gxt[gxb + 2*16384];
      float go = gbuf[3*64 + o] + Gxt[gxb + 3*16384];
      float cp = cbuf[o];
      float c = sigf(gf)*cp + sigf(gi)*tanhf(gu);
      float h = sigf(go)*tanhf(c);
      cbuf[o] = c;
      size_t oidx = ((size_t)(m*LL + t))*HH + j0 + jj;
      hs[oidx] = h;
      cs[oidx] = c;
      hs_bf[oidx] = f2bf(h);
    }
    if (t < LL-1){              // last step: kernel boundary publishes
      target += 256;
      gridbar(bar, target);
    }
  }
}

// ---------------------------------------------------------------------------
// Per-position rank-MLP score + gumbel noise (fp32 — decision path).
__global__ __launch_bounds__(128) void k_score(const float* __restrict__ R1t,
    const float* __restrict__ R2, const float* __restrict__ hs,
    const float* __restrict__ gumbel_u, float* __restrict__ score,
    float* __restrict__ snoisy){
  __shared__ float hsm[HH];
  __shared__ float red[128];
  int bt = blockIdx.x;
  int tid = threadIdx.x;
  for (int i = tid; i < HH; i += 128) hsm[i] = hs[(size_t)bt*HH + i];
  __syncthreads();
  float acc = 0.f;
  for (int k = 0; k < HH; ++k) acc += R1t[(size_t)k*RANKH + tid] * hsm[k];
  red[tid] = fmaxf(acc, 0.f) * R2[tid];
  __syncthreads();
  for (int s = 64; s > 0; s >>= 1){
    if (tid < s) red[tid] += red[tid+s];
    __syncthreads();
  }
  if (tid == 0){
    float s = red[0];
    float u = gumbel_u[bt];
    float noise = -logf(-logf(u));
    score[bt]  = s;
    snoisy[bt] = s + noise;
  }
}

// ---------------------------------------------------------------------------
// Build the tree structure for all batches. 1 block, 64 threads.
// level_count[0] <- number of levels (max height).
__global__ __launch_bounds__(64) void k_build(const float* __restrict__ score,
    const float* __restrict__ snoisy, const int* __restrict__ length,
    int* __restrict__ node_l, int* __restrict__ node_r, int* __restrict__ node_x,
    int* __restrict__ node_lvl, int* __restrict__ node_b, int* __restrict__ node_root,
    int* __restrict__ level_count, int* __restrict__ level_off, int* __restrict__ order){
  __shared__ float sc[BB*LL], sn[BB*LL];
  __shared__ int lcount[MAXLVL+1], lcur[MAXLVL+1], loff[MAXLVL+1];
  __shared__ int percnt[BB];
  int tid = threadIdx.x;
  for (int i = tid; i < BB*LL; i += 64){ sc[i] = score[i]; sn[i] = snoisy[i]; }
  for (int i = tid; i <= MAXLVL; i += 64){ lcount[i] = 0; lcur[i] = 0; }
  __syncthreads();
  if (tid < BB){
    int b = tid;
    int len = length[b];
    if (len > LL) len = LL;
    int qs[MAXN], qe[MAXN], qn[MAXN];
    int qh = 0, qt = 0, cnt = 0;
    int rootn = cnt++;
    qs[qt] = 0; qe[qt] = len; qn[qt] = rootn; qt++;
    while (qh < qt){
      int s0 = qs[qh], e0 = qe[qh], nid = qn[qh]; qh++;
      float best = sc[b*LL + s0]; int pos = s0;
      for (int t2 = s0+1; t2 < e0; ++t2){
        float v = sc[b*LL + t2];
        if (v > best){ best = v; pos = t2; }
      }
      float bestn = sn[b*LL + s0]; int js = s0;
      for (int t2 = s0+1; t2 < e0; ++t2){
        float v = sn[b*LL + t2];
        if (v > bestn){ bestn = v; js = t2; }
      }
      int gid = b*MAXN + nid;
      node_x[gid] = js;
      node_b[gid] = b;
      node_root[gid] = (nid == 0) ? 1 : 0;
      int ln = pos - s0, enc_l, enc_r;
      if (ln <= 0) enc_l = -1;
      else if (ln == 1) enc_l = 10000 + s0;
      else { int c2 = cnt++; enc_l = b*MAXN + c2; qs[qt]=s0; qe[qt]=pos; qn[qt]=c2; qt++; }
      int rn = e0 - (pos+1);
      if (rn <= 0) enc_r = -1;
      else if (rn == 1) enc_r = 10000 + (pos+1);
      else { int c2 = cnt++; enc_r = b*MAXN + c2; qs[qt]=pos+1; qe[qt]=e0; qn[qt]=c2; qt++; }
      node_l[gid] = enc_l; node_r[gid] = enc_r;
    }
    for (int i = cnt-1; i >= 0; --i){
      int gid = b*MAXN + i;
      int el = node_l[gid], er = node_r[gid];
      int llv = (el >= 0 && el < 10000) ? node_lvl[el] : 0;
      int rlv = (er >= 0 && er < 10000) ? node_lvl[er] : 0;
      node_lvl[gid] = 1 + (llv > rlv ? llv : rlv);
    }
    for (int i = 0; i < cnt; ++i) atomicAdd(&lcount[node_lvl[b*MAXN + i]], 1);
    percnt[b] = cnt;
  }
  __syncthreads();
  if (tid == 0){
    int off = 0, nlev = 0;
    for (int lv = 1; lv <= MAXLVL; ++lv){
      loff[lv] = off;
      level_off[lv] = off;
      level_count[lv] = lcount[lv];
      if (lcount[lv] > 0) nlev = lv;
      off += lcount[lv];
    }
    level_count[0] = nlev;
  }
  __syncthreads();
  if (tid < BB){
    int b = tid;
    int cnt = percnt[b];
    for (int i = 0; i < cnt; ++i){
      int gid = b*MAXN + i;
      int lv = node_lvl[gid];
      int p = atomicAdd(&lcur[lv], 1);
      order[loff[lv] + p] = gid;
    }
  }
}

// ---------------------------------------------------------------------------
// Persistent tree composition. Phase A: bf16 MFMA GEMM, fragments loaded
// DIRECTLY from global (A/B rows are contiguous; 16B/lane) — no LDS, no
// syncthreads in the K-loop, fully pipelineable. Null children -> zrow.
// Phase B: bias + nary tree-LSTM cell epilogue.
__global__ __launch_bounds__(256, 1) void k_tree(
    const unsigned short* __restrict__ Wc_bf,
    const unsigned short* __restrict__ hs_bf,
    unsigned short* __restrict__ nodeH_bf,
    const unsigned short* __restrict__ zrow,
    const float* __restrict__ bc, const float* __restrict__ cs,
    float* __restrict__ nodeC,
    const int* __restrict__ node_l, const int* __restrict__ node_r,
    const int* __restrict__ node_x, const int* __restrict__ node_b,
    const int* __restrict__ node_root, const int* __restrict__ level_count,
    const int* __restrict__ level_off, const int* __restrict__ order,
    float* __restrict__ gates, float* __restrict__ out,
    unsigned* __restrict__ bar){
  int tid = threadIdx.x;
  int lane = tid & 63;
  int wave = tid >> 6;
  int wm = wave >> 1, wn = wave & 1;
  int fr = lane & 15, fk = (lane >> 4) * 8;
  int nlev = level_count[0];
  unsigned target = 0;
  for (int lvl = 1; lvl <= nlev; ++lvl){
    int n = level_count[lvl];
    int loffv = level_off[lvl];
    int ntg = (n + 63) >> 6;
    int tiles = ntg * 96;
    // ---- Phase A: GEMM tiles (64 nodes x 64 Wc rows x K=3072) ----
    for (int tile = blockIdx.x; tile < tiles; tile += 256){
      int ng = tile / 96, rg = tile - ng*96;
      const unsigned short* pa[2][3];
      #pragma unroll
      for (int ti = 0; ti < 2; ++ti){
        int slot = ng*64 + wm*32 + ti*16 + fr;
        if (slot < n){
          int gid = order[loffv + slot];
          int b = node_b[gid];
          int el = node_l[gid], er = node_r[gid], xt = node_x[gid];
          pa[ti][0] = (el < 0) ? zrow : (el >= 10000 ? hs_bf + (size_t)(b*LL + (el-10000))*HH
                                                     : nodeH_bf + (size_t)el*HH);
          pa[ti][1] = (er < 0) ? zrow : (er >= 10000 ? hs_bf + (size_t)(b*LL + (er-10000))*HH
                                                     : nodeH_bf + (size_t)er*HH);
          pa[ti][2] = hs_bf + (size_t)(b*LL + xt)*HH;
        } else {
          pa[ti][0] = zrow; pa[ti][1] = zrow; pa[ti][2] = zrow;
        }
      }
      const unsigned short* pb0 = Wc_bf + (size_t)(rg*64 + wn*32 + fr)*K3H + fk;
      const unsigned short* pb1 = pb0 + (size_t)16*K3H;
      f32x4 acc[2][2] = {{{0.f,0.f,0.f,0.f},{0.f,0.f,0.f,0.f}},
                         {{0.f,0.f,0.f,0.f},{0.f,0.f,0.f,0.f}}};
      #pragma unroll
      for (int part = 0; part < 3; ++part){
        const unsigned short* a0p = pa[0][part] + fk;
        const unsigned short* a1p = pa[1][part] + fk;
        const unsigned short* b0p = pb0 + part*1024;
        const unsigned short* b1p = pb1 + part*1024;
        #pragma unroll 8
        for (int kc = 0; kc < 1024; kc += 32){
          bf16x8 a0 = *(const bf16x8*)(a0p + kc);
          bf16x8 a1 = *(const bf16x8*)(a1p + kc);
          bf16x8 b0 = *(const bf16x8*)(b0p + kc);
          bf16x8 b1 = *(const bf16x8*)(b1p + kc);
          acc[0][0] = __builtin_amdgcn_mfma_f32_16x16x32_bf16(a0, b0, acc[0][0], 0, 0, 0);
          acc[0][1] = __builtin_amdgcn_mfma_f32_16x16x32_bf16(a0, b1, acc[0][1], 0, 0, 0);
          acc[1][0] = __builtin_amdgcn_mfma_f32_16x16x32_bf16(a1, b0, acc[1][0], 0, 0, 0);
          acc[1][1] = __builtin_amdgcn_mfma_f32_16x16x32_bf16(a1, b1, acc[1][1], 0, 0, 0);
        }
      }
      int crow4 = (lane >> 4)*4, ccol = lane & 15;
      #pragma unroll
      for (int ti = 0; ti < 2; ++ti)
        #pragma unroll
        for (int tj = 0; tj < 2; ++tj)
          #pragma unroll
          for (int r = 0; r < 4; ++r){
            int m = wm*32 + ti*16 + crow4 + r;
            int nn = wn*32 + tj*16 + ccol;
            gates[(size_t)(ng*64 + m)*NG6 + rg*64 + nn] = acc[ti][tj][r];
          }
    }
    target += 256;
    gridbar(bar, target);
    // ---- Phase B: epilogue ----
    int items = n * 4;
    for (int it = blockIdx.x; it < items; it += 256){
      int ns = it >> 2;
      int j = (it & 3)*256 + tid;
      int gid = order[loffv + ns];
      int b = node_b[gid];
      int el = node_l[gid], er = node_r[gid], xt = node_x[gid];
      float gg[6];
      #pragma unroll
      for (int q = 0; q < 6; ++q)
        gg[q] = bc[q*HH + j] + gates[(size_t)ns*NG6 + q*HH + j];
      float lc = (el < 0) ? 0.f : (el >= 10000 ? cs[(size_t)(b*LL + (el-10000))*HH + j]
                                               : nodeC[(size_t)el*HH + j]);
      float rc = (er < 0) ? 0.f : (er >= 10000 ? cs[(size_t)(b*LL + (er-10000))*HH + j]
                                               : nodeC[(size_t)er*HH + j]);
      float xc = cs[(size_t)(b*LL + xt)*HH + j];
      float c = sigf(gg[0])*tanhf(gg[4]) + sigf(gg[1])*lc + sigf(gg[2])*rc + sigf(gg[3])*xc;
      float h = sigf(gg[5])*tanhf(c);
      nodeH_bf[(size_t)gid*HH + j] = f2bf(h);
      nodeC[(size_t)gid*HH + j] = c;
      if (node_root[gid]){
        out[(size_t)b*HH + j] = h;
        out[(size_t)BB*HH + (size_t)b*HH + j] = c;
      }
    }
    if (lvl < nlev){            // last level: kernel boundary publishes out
      target += 256;
      gridbar(bar, target);
    }
  }
}

// ---------------------------------------------------------------------------
extern "C" void kernel_launch(void* const* d_in, const int* in_sizes, int n_in,
                              void* d_out, int out_size, void* d_ws, size_t ws_size,
                              hipStream_t stream){
  const float* se  = (const float*)d_in[0];
  const float* gu  = (const float*)d_in[1];
  const float* Wih = (const float*)d_in[2];
  const float* Whh = (const float*)d_in[3];
  const float* bih = (const float*)d_in[4];
  const float* bhh = (const float*)d_in[5];
  const float* R1  = (const float*)d_in[6];
  const float* R2  = (const float*)d_in[7];
  const float* Wc  = (const float*)d_in[8];
  const float* bc  = (const float*)d_in[9];
  const int*   len = (const int*)d_in[10];
  float* out = (float*)d_out;                 // [2,16,1024] fp32

  float* ws = (float*)d_ws;
  size_t off = 0;
  float* R1t   = ws + off; off += (size_t)HH*RANKH;
  float* Gx    = ws + off; off += (size_t)BB*LL*NG4;     // [m][t][4096]
  float* Gxt   = ws + off; off += (size_t)BB*LL*NG4;     // [t][4096][m]
  float* hs    = ws + off; off += (size_t)BB*LL*HH;
  float* cs    = ws + off; off += (size_t)BB*LL*HH;
  float* nodeC = ws + off; off += (size_t)TOTN*HH;
  float* gates = ws + off; off += (size_t)MAXNPL*NG6;
  unsigned short* Wc_bf    = (unsigned short*)(ws + off); off += (size_t)NG6*K3H/2;
  unsigned short* hs_bf    = (unsigned short*)(ws + off); off += (size_t)BB*LL*HH/2;
  unsigned short* nodeH_bf = (unsigned short*)(ws + off); off += (size_t)TOTN*HH/2 + 512;
  unsigned short* zrow     = (unsigned short*)(ws + off); off += 512;  // 1024 zero bf16
  float* score = ws + off; off += 1024;
  float* snoi  = ws + off; off += 1024;
  unsigned* bar = (unsigned*)(ws + off); off += 64;
  int* ib = (int*)(ws + off);
  int* node_l    = ib; ib += 768;
  int* node_r    = ib; ib += 768;
  int* node_x    = ib; ib += 768;
  int* node_lvl  = ib; ib += 768;
  int* node_b    = ib; ib += 768;
  int* node_root = ib; ib += 768;
  int* level_count = ib; ib += 64;
  int* level_off   = ib; ib += 64;
  int* order       = ib; ib += 768;

  // 0. zero barrier counters + dummy zero row (ws poisoned every launch)
  k_init<<<1, 256, 0, stream>>>(bar, zrow);
  // 1. R1 transpose + Wc bf16 conversion
  k_transpose<<<dim3(32, 4), dim3(32, 8), 0, stream>>>(R1, R1t, RANKH, HH);
  k_cvt_bf16<<<(NG6*K3H)/1024, 256, 0, stream>>>(Wc, Wc_bf, NG6*K3H);
  // 2. input-side gate GEMM (+ both biases), then transpose for the scan
  k_gemm_gx<<<dim3(12, 64), 256, 0, stream>>>(se, Wih, bih, bhh, Gx, BB*LL, NG4, HH);
  k_gx_t<<<dim3(48, 16), 256, 0, stream>>>(Gx, Gxt);
  // 3. persistent recurrent LSTM scan (48 steps, cheap grid barriers)
  k_lstm_scan<<<256, 256, 0, stream>>>(Whh, Gxt, hs, cs, hs_bf, bar);
  // 4. per-position scores + gumbel noise (fp32)
  k_score<<<BB*LL, 128, 0, stream>>>(R1t, R2, hs, gu, score, snoi);
  // 5. tree structure
  k_build<<<1, 64, 0, stream>>>(score, snoi, len, node_l, node_r, node_x,
                                node_lvl, node_b, node_root,
                                level_count, level_off, order);
  // 6. persistent level-by-level nary composition
  k_tree<<<256, 256, 0, stream>>>(Wc_bf, hs_bf, nodeH_bf, zrow, bc, cs, nodeC,
                                  node_l, node_r, node_x, node_b, node_root,
                                  level_count, level_off, order,
                                  gates, out, bar + 8);
}

// Round 6
// 2495.391 us; speedup vs baseline: 1.6899x; 1.0656x over previous
//
#include <hip/hip_runtime.h>
#include <math.h>

#define BB 16
#define LL 48
#define HH 1024
#define NG4 4096      // 4*H
#define NG6 6144      // 6*H
#define K3H 3072      // 3*H
#define RANKH 128
#define MAXN 47       // max nodes per batch (len-1 <= 47)
#define TOTN (BB*MAXN)
#define MAXLVL 48
#define MAXNPL 384    // max nodes in one level

#define CH 20         // padded floats per 16-float k-chunk in scan LDS
#define HROW (64*CH)  // 1280 floats per m-row

typedef __attribute__((ext_vector_type(8))) short bf16x8;
typedef __attribute__((ext_vector_type(4))) float f32x4;

__device__ __forceinline__ float sigf(float x){ return 1.f/(1.f + expf(-x)); }

__device__ __forceinline__ unsigned short f2bf(float f){
  union { float f; unsigned u; } v; v.f = f;
  unsigned r = v.u + 0x7fff + ((v.u >> 16) & 1);
  return (unsigned short)(r >> 16);
}

// LLC-coherent scalar access (agent-scope relaxed atomics -> sc0|sc1: bypass
// L1/L2, served by the device-coherent Infinity Cache; no fences needed).
__device__ __forceinline__ void st_llc(float* p, float v){
  __hip_atomic_store(p, v, __ATOMIC_RELAXED, __HIP_MEMORY_SCOPE_AGENT);
}
__device__ __forceinline__ float ld_llc(const float* p){
  return __hip_atomic_load(p, __ATOMIC_RELAXED, __HIP_MEMORY_SCOPE_AGENT);
}

// Fence-free barrier for producers whose data was stored via st_llc.
// s_waitcnt vmcnt(0) guarantees the wave's LLC stores are ack'd before the
// arrival add; consumers read via ld_llc so no invalidate is required.
__device__ __forceinline__ void gridbar_raw(unsigned* bar, unsigned target){
  __syncthreads();
  if (threadIdx.x == 0){
    __builtin_amdgcn_s_waitcnt(0x0F70);   // vmcnt(0) only
    __hip_atomic_fetch_add(bar, 1u, __ATOMIC_RELAXED, __HIP_MEMORY_SCOPE_AGENT);
    while (__hip_atomic_load(bar, __ATOMIC_RELAXED, __HIP_MEMORY_SCOPE_AGENT) < target)
      __builtin_amdgcn_s_sleep(1);
  }
  __syncthreads();
}

// Barrier for normal cached stores: release add (wb) + relaxed poll + ONE
// acquire (inv) after the spin. Used by k_tree (phases use cached stores).
__device__ __forceinline__ void gridbar(unsigned* bar, unsigned target){
  __syncthreads();
  if (threadIdx.x == 0){
    __hip_atomic_fetch_add(bar, 1u, __ATOMIC_RELEASE, __HIP_MEMORY_SCOPE_AGENT);
    while (__hip_atomic_load(bar, __ATOMIC_RELAXED, __HIP_MEMORY_SCOPE_AGENT) < target)
      __builtin_amdgcn_s_sleep(2);
    (void)__hip_atomic_load(bar, __ATOMIC_ACQUIRE, __HIP_MEMORY_SCOPE_AGENT);
  }
  __syncthreads();
}

// ---------------------------------------------------------------------------
// Zero barrier counters ([0]=scan, [8]=tree) + the zero dummy row.
__global__ __launch_bounds__(256) void k_init(unsigned* bar, unsigned short* zrow){
  int tid = threadIdx.x;
  if (tid < 16) bar[tid] = 0u;
  for (int i = tid; i < 1024; i += 256) zrow[i] = 0;
}

// ---------------------------------------------------------------------------
// fp32 -> bf16 (RNE), vectorized. n multiple of 1024.
__global__ __launch_bounds__(256) void k_cvt_bf16(const float* __restrict__ in,
    unsigned short* __restrict__ out, int n){
  int i = (blockIdx.x*256 + threadIdx.x)*4;
  if (i >= n) return;
  float4 v = *(const float4*)(in + i);
  ushort4 o;
  o.x = f2bf(v.x); o.y = f2bf(v.y); o.z = f2bf(v.z); o.w = f2bf(v.w);
  *(ushort4*)(out + i) = o;
}

// ---------------------------------------------------------------------------
// Generic 32x32 LDS-tiled transpose: out[C][R] = in[R][C]^T  (R1 only)
__global__ __launch_bounds__(256) void k_transpose(const float* __restrict__ in,
                                                   float* __restrict__ out, int R, int C){
  __shared__ float t[32][33];
  int bx = blockIdx.x*32, by = blockIdx.y*32;
  int x = threadIdx.x, y = threadIdx.y;   // block (32,8)
  #pragma unroll
  for (int i = 0; i < 32; i += 8){
    int r = by + y + i, c = bx + x;
    if (r < R && c < C) t[y+i][x] = in[(size_t)r*C + c];
  }
  __syncthreads();
  #pragma unroll
  for (int i = 0; i < 32; i += 8){
    int r = bx + y + i, c = by + x;       // out dims [C][R]
    if (r < C && c < R) out[(size_t)r*R + c] = t[x][y+i];
  }
}

// ---------------------------------------------------------------------------
// Gx[m][n] = sum_k se[m][k]*Wih[n][k] + bih[n] + bhh[n]   (fp32 — decision path)
__global__ __launch_bounds__(256) void k_gemm_gx(const float* __restrict__ A,
    const float* __restrict__ Bw, const float* __restrict__ bih,
    const float* __restrict__ bhh, float* __restrict__ Cout, int M, int N, int K){
  __shared__ float as[16][68];
  __shared__ float bs[16][68];
  int m0 = blockIdx.x*64, n0 = blockIdx.y*64;
  int tid = threadIdx.x;
  int mt = tid & 15, nt = tid >> 4;
  float acc[4][4] = {};
  for (int k0 = 0; k0 < K; k0 += 16){
    #pragma unroll
    for (int it = 0; it < 4; ++it){
      int idx = it*256 + tid;
      int kk = idx & 15, mm = idx >> 4;
      as[kk][mm] = A[(size_t)(m0+mm)*K + k0 + kk];
      bs[kk][mm] = Bw[(size_t)(n0+mm)*K + k0 + kk];
    }
    __syncthreads();
    #pragma unroll
    for (int kk = 0; kk < 16; ++kk){
      float a4[4], b4[4];
      #pragma unroll
      for (int i = 0; i < 4; ++i) a4[i] = as[kk][mt*4+i];
      #pragma unroll
      for (int i = 0; i < 4; ++i) b4[i] = bs[kk][nt*4+i];
      #pragma unroll
      for (int i = 0; i < 4; ++i)
        #pragma unroll
        for (int j2 = 0; j2 < 4; ++j2) acc[i][j2] += a4[i]*b4[j2];
    }
    __syncthreads();
  }
  #pragma unroll
  for (int i = 0; i < 4; ++i){
    int m = m0 + mt*4 + i;
    #pragma unroll
    for (int j2 = 0; j2 < 4; ++j2){
      int n = n0 + nt*4 + j2;
      Cout[(size_t)m*N + n] = acc[i][j2] + bih[n] + bhh[n];
    }
  }
}

// ---------------------------------------------------------------------------
// Gx [m][t][4096] -> Gxt [t][4096][m]  (for coalesced per-step gate reads)
__global__ __launch_bounds__(256) void k_gx_t(const float* __restrict__ Gx,
                                              float* __restrict__ Gxt){
  __shared__ float t2[16][257];
  int t = blockIdx.x;       // 48
  int rc = blockIdx.y;      // 16 chunks of 256 rows
  int tid = threadIdx.x;
  #pragma unroll
  for (int m = 0; m < 16; ++m)
    t2[m][tid] = Gx[((size_t)(m*48 + t))*4096 + rc*256 + tid];
  __syncthreads();
  int rl = tid >> 4, m = tid & 15;
  #pragma unroll
  for (int i = 0; i < 16; ++i){
    int r = rc*256 + i*16 + rl;
    Gxt[((size_t)t*4096 + r)*16 + m] = t2[m][i*16 + rl];
  }
}

// ---------------------------------------------------------------------------
// Persistent LSTM scan: 256 blocks x 256 threads, 1 block/CU.
// h exchanged through LLC (st_llc/ld_llc) — NO L2 writeback/invalidate.
// Whh held in registers (w[4][16] per lane, lane=k-chunk of 16).
__global__ __launch_bounds__(256, 1) void k_lstm_scan(
    const float* __restrict__ Whh, const float* __restrict__ Gxt,
    float* __restrict__ hs, float* __restrict__ cs,
    unsigned short* __restrict__ hs_bf, unsigned* __restrict__ bar){
  __shared__ float smem[16*HROW];   // 80KB: h-stage; overlaid by reduce partials
  __shared__ float gbuf[4*64];
  __shared__ float cbuf[64];
  int tid = threadIdx.x;
  int g = tid >> 6, kc = tid & 63;
  int j0 = blockIdx.x * 4;
  float w[4][16];
  #pragma unroll
  for (int jj = 0; jj < 4; ++jj){
    const float* src = Whh + (size_t)(g*1024 + j0 + jj)*1024 + kc*16;
    #pragma unroll
    for (int kk = 0; kk < 16; kk += 4){
      float4 v = *(const float4*)(src + kk);
      w[jj][kk]=v.x; w[jj][kk+1]=v.y; w[jj][kk+2]=v.z; w[jj][kk+3]=v.w;
    }
  }
  if (tid < 64) cbuf[tid] = 0.f;
  unsigned target = 0;
  for (int t = 0; t < LL; ++t){
    float G = 0.f;
    if (t > 0){
      // stage h_{t-1} into LDS via LLC-coherent scalar loads
      #pragma unroll
      for (int m = 0; m < 16; ++m){
        const float* src = hs + ((size_t)(m*LL + t-1))*HH + (tid<<2);
        float4 v;
        v.x = ld_llc(src+0); v.y = ld_llc(src+1);
        v.z = ld_llc(src+2); v.w = ld_llc(src+3);
        *(float4*)&smem[m*HROW + (tid>>2)*CH + (tid&3)*4] = v;
      }
      __syncthreads();
      float acc[4][16];
      #pragma unroll 4
      for (int m = 0; m < 16; ++m){
        const float* hb = &smem[m*HROW + kc*CH];
        float4 h0 = *(const float4*)(hb);
        float4 h1 = *(const float4*)(hb+4);
        float4 h2 = *(const float4*)(hb+8);
        float4 h3 = *(const float4*)(hb+12);
        #pragma unroll
        for (int jj = 0; jj < 4; ++jj){
          float s = w[jj][0]*h0.x + w[jj][1]*h0.y + w[jj][2]*h0.z + w[jj][3]*h0.w
                  + w[jj][4]*h1.x + w[jj][5]*h1.y + w[jj][6]*h1.z + w[jj][7]*h1.w
                  + w[jj][8]*h2.x + w[jj][9]*h2.y + w[jj][10]*h2.z + w[jj][11]*h2.w
                  + w[jj][12]*h3.x + w[jj][13]*h3.y + w[jj][14]*h3.z + w[jj][15]*h3.w;
          acc[jj][m] = s;
        }
      }
      __syncthreads();   // hsm reads done; smem reused as reduce partials
      #pragma unroll
      for (int m = 0; m < 16; ++m){
        float4 v;
        v.x = acc[0][m]; v.y = acc[1][m]; v.z = acc[2][m]; v.w = acc[3][m];
        *(float4*)&smem[(size_t)(g*64 + kc)*68 + m*4] = v;
      }
      __syncthreads();
      {
        float s0=0.f,s1=0.f,s2=0.f,s3=0.f;
        #pragma unroll 4
        for (int l = 0; l < 64; l += 4){
          s0 += smem[(size_t)(g*64 + l  )*68 + kc];
          s1 += smem[(size_t)(g*64 + l+1)*68 + kc];
          s2 += smem[(size_t)(g*64 + l+2)*68 + kc];
          s3 += smem[(size_t)(g*64 + l+3)*68 + kc];
        }
        G = (s0+s1)+(s2+s3);
      }
    }
    gbuf[g*64 + kc] = G;
    __syncthreads();
    if (g == 0){
      int o = kc;               // o = m*4 + jj
      int jj = o & 3, m = o >> 2;
      size_t gxb = ((size_t)t*NG4 + j0 + jj)*16 + m;
      float gi = gbuf[0*64 + o] + Gxt[gxb + 0*16384];
      float gf = gbuf[1*64 + o] + Gxt[gxb + 1*16384];
      float gu = gbuf[2*64 + o] + Gxt[gxb + 2*16384];
      float go = gbuf[3*64 + o] + Gxt[gxb + 3*16384];
      float cp = cbuf[o];
      float c = sigf(gf)*cp + sigf(gi)*tanhf(gu);
      float h = sigf(go)*tanhf(c);
      cbuf[o] = c;
      size_t oidx = ((size_t)(m*LL + t))*HH + j0 + jj;
      st_llc(&hs[oidx], h);     // LLC write-through: visible without fences
      cs[oidx] = c;             // read only after kernel boundary
      hs_bf[oidx] = f2bf(h);    // read only after kernel boundary
    }
    if (t < LL-1){
      target += 256;
      gridbar_raw(bar, target);
    }
  }
}

// ---------------------------------------------------------------------------
// Per-position rank-MLP score + gumbel noise (fp32 — decision path).
__global__ __launch_bounds__(128) void k_score(const float* __restrict__ R1t,
    const float* __restrict__ R2, const float* __restrict__ hs,
    const float* __restrict__ gumbel_u, float* __restrict__ score,
    float* __restrict__ snoisy){
  __shared__ float hsm[HH];
  __shared__ float red[128];
  int bt = blockIdx.x;
  int tid = threadIdx.x;
  for (int i = tid; i < HH; i += 128) hsm[i] = hs[(size_t)bt*HH + i];
  __syncthreads();
  float acc = 0.f;
  for (int k = 0; k < HH; ++k) acc += R1t[(size_t)k*RANKH + tid] * hsm[k];
  red[tid] = fmaxf(acc, 0.f) * R2[tid];
  __syncthreads();
  for (int s = 64; s > 0; s >>= 1){
    if (tid < s) red[tid] += red[tid+s];
    __syncthreads();
  }
  if (tid == 0){
    float s = red[0];
    float u = gumbel_u[bt];
    float noise = -logf(-logf(u));
    score[bt]  = s;
    snoisy[bt] = s + noise;
  }
}

// ---------------------------------------------------------------------------
// Build the tree structure for all batches. 1 block, 64 threads.
// level_count[0] <- number of levels (max height).
__global__ __launch_bounds__(64) void k_build(const float* __restrict__ score,
    const float* __restrict__ snoisy, const int* __restrict__ length,
    int* __restrict__ node_l, int* __restrict__ node_r, int* __restrict__ node_x,
    int* __restrict__ node_lvl, int* __restrict__ node_b, int* __restrict__ node_root,
    int* __restrict__ level_count, int* __restrict__ level_off, int* __restrict__ order){
  __shared__ float sc[BB*LL], sn[BB*LL];
  __shared__ int lcount[MAXLVL+1], lcur[MAXLVL+1], loff[MAXLVL+1];
  __shared__ int percnt[BB];
  int tid = threadIdx.x;
  for (int i = tid; i < BB*LL; i += 64){ sc[i] = score[i]; sn[i] = snoisy[i]; }
  for (int i = tid; i <= MAXLVL; i += 64){ lcount[i] = 0; lcur[i] = 0; }
  __syncthreads();
  if (tid < BB){
    int b = tid;
    int len = length[b];
    if (len > LL) len = LL;
    int qs[MAXN], qe[MAXN], qn[MAXN];
    int qh = 0, qt = 0, cnt = 0;
    int rootn = cnt++;
    qs[qt] = 0; qe[qt] = len; qn[qt] = rootn; qt++;
    while (qh < qt){
      int s0 = qs[qh], e0 = qe[qh], nid = qn[qh]; qh++;
      float best = sc[b*LL + s0]; int pos = s0;
      for (int t2 = s0+1; t2 < e0; ++t2){
        float v = sc[b*LL + t2];
        if (v > best){ best = v; pos = t2; }
      }
      float bestn = sn[b*LL + s0]; int js = s0;
      for (int t2 = s0+1; t2 < e0; ++t2){
        float v = sn[b*LL + t2];
        if (v > bestn){ bestn = v; js = t2; }
      }
      int gid = b*MAXN + nid;
      node_x[gid] = js;
      node_b[gid] = b;
      node_root[gid] = (nid == 0) ? 1 : 0;
      int ln = pos - s0, enc_l, enc_r;
      if (ln <= 0) enc_l = -1;
      else if (ln == 1) enc_l = 10000 + s0;
      else { int c2 = cnt++; enc_l = b*MAXN + c2; qs[qt]=s0; qe[qt]=pos; qn[qt]=c2; qt++; }
      int rn = e0 - (pos+1);
      if (rn <= 0) enc_r = -1;
      else if (rn == 1) enc_r = 10000 + (pos+1);
      else { int c2 = cnt++; enc_r = b*MAXN + c2; qs[qt]=pos+1; qe[qt]=e0; qn[qt]=c2; qt++; }
      node_l[gid] = enc_l; node_r[gid] = enc_r;
    }
    for (int i = cnt-1; i >= 0; --i){
      int gid = b*MAXN + i;
      int el = node_l[gid], er = node_r[gid];
      int llv = (el >= 0 && el < 10000) ? node_lvl[el] : 0;
      int rlv = (er >= 0 && er < 10000) ? node_lvl[er] : 0;
      node_lvl[gid] = 1 + (llv > rlv ? llv : rlv);
    }
    for (int i = 0; i < cnt; ++i) atomicAdd(&lcount[node_lvl[b*MAXN + i]], 1);
    percnt[b] = cnt;
  }
  __syncthreads();
  if (tid == 0){
    int off = 0, nlev = 0;
    for (int lv = 1; lv <= MAXLVL; ++lv){
      loff[lv] = off;
      level_off[lv] = off;
      level_count[lv] = lcount[lv];
      if (lcount[lv] > 0) nlev = lv;
      off += lcount[lv];
    }
    level_count[0] = nlev;
  }
  __syncthreads();
  if (tid < BB){
    int b = tid;
    int cnt = percnt[b];
    for (int i = 0; i < cnt; ++i){
      int gid = b*MAXN + i;
      int lv = node_lvl[gid];
      int p = atomicAdd(&lcur[lv], 1);
      order[loff[lv] + p] = gid;
    }
  }
}

// ---------------------------------------------------------------------------
// Persistent tree composition. Phase A: bf16 MFMA GEMM, fragments loaded
// DIRECTLY from global — no LDS, no syncthreads in the K-loop. Null -> zrow.
// Phase B: bias + nary tree-LSTM cell epilogue.
__global__ __launch_bounds__(256, 1) void k_tree(
    const unsigned short* __restrict__ Wc_bf,
    const unsigned short* __restrict__ hs_bf,
    unsigned short* __restrict__ nodeH_bf,
    const unsigned short* __restrict__ zrow,
    const float* __restrict__ bc, const float* __restrict__ cs,
    float* __restrict__ nodeC,
    const int* __restrict__ node_l, const int* __restrict__ node_r,
    const int* __restrict__ node_x, const int* __restrict__ node_b,
    const int* __restrict__ node_root, const int* __restrict__ level_count,
    const int* __restrict__ level_off, const int* __restrict__ order,
    float* __restrict__ gates, float* __restrict__ out,
    unsigned* __restrict__ bar){
  int tid = threadIdx.x;
  int lane = tid & 63;
  int wave = tid >> 6;
  int wm = wave >> 1, wn = wave & 1;
  int fr = lane & 15, fk = (lane >> 4) * 8;
  int nlev = level_count[0];
  unsigned target = 0;
  for (int lvl = 1; lvl <= nlev; ++lvl){
    int n = level_count[lvl];
    int loffv = level_off[lvl];
    int ntg = (n + 63) >> 6;
    int tiles = ntg * 96;
    // ---- Phase A: GEMM tiles (64 nodes x 64 Wc rows x K=3072) ----
    for (int tile = blockIdx.x; tile < tiles; tile += 256){
      int ng = tile / 96, rg = tile - ng*96;
      const unsigned short* pa[2][3];
      #pragma unroll
      for (int ti = 0; ti < 2; ++ti){
        int slot = ng*64 + wm*32 + ti*16 + fr;
        if (slot < n){
          int gid = order[loffv + slot];
          int b = node_b[gid];
          int el = node_l[gid], er = node_r[gid], xt = node_x[gid];
          pa[ti][0] = (el < 0) ? zrow : (el >= 10000 ? hs_bf + (size_t)(b*LL + (el-10000))*HH
                                                     : nodeH_bf + (size_t)el*HH);
          pa[ti][1] = (er < 0) ? zrow : (er >= 10000 ? hs_bf + (size_t)(b*LL + (er-10000))*HH
                                                     : nodeH_bf + (size_t)er*HH);
          pa[ti][2] = hs_bf + (size_t)(b*LL + xt)*HH;
        } else {
          pa[ti][0] = zrow; pa[ti][1] = zrow; pa[ti][2] = zrow;
        }
      }
      const unsigned short* pb0 = Wc_bf + (size_t)(rg*64 + wn*32 + fr)*K3H + fk;
      const unsigned short* pb1 = pb0 + (size_t)16*K3H;
      f32x4 acc[2][2] = {{{0.f,0.f,0.f,0.f},{0.f,0.f,0.f,0.f}},
                         {{0.f,0.f,0.f,0.f},{0.f,0.f,0.f,0.f}}};
      #pragma unroll
      for (int part = 0; part < 3; ++part){
        const unsigned short* a0p = pa[0][part] + fk;
        const unsigned short* a1p = pa[1][part] + fk;
        const unsigned short* b0p = pb0 + part*1024;
        const unsigned short* b1p = pb1 + part*1024;
        #pragma unroll 8
        for (int kc = 0; kc < 1024; kc += 32){
          bf16x8 a0 = *(const bf16x8*)(a0p + kc);
          bf16x8 a1 = *(const bf16x8*)(a1p + kc);
          bf16x8 b0 = *(const bf16x8*)(b0p + kc);
          bf16x8 b1 = *(const bf16x8*)(b1p + kc);
          acc[0][0] = __builtin_amdgcn_mfma_f32_16x16x32_bf16(a0, b0, acc[0][0], 0, 0, 0);
          acc[0][1] = __builtin_amdgcn_mfma_f32_16x16x32_bf16(a0, b1, acc[0][1], 0, 0, 0);
          acc[1][0] = __builtin_amdgcn_mfma_f32_16x16x32_bf16(a1, b0, acc[1][0], 0, 0, 0);
          acc[1][1] = __builtin_amdgcn_mfma_f32_16x16x32_bf16(a1, b1, acc[1][1], 0, 0, 0);
        }
      }
      int crow4 = (lane >> 4)*4, ccol = lane & 15;
      #pragma unroll
      for (int ti = 0; ti < 2; ++ti)
        #pragma unroll
        for (int tj = 0; tj < 2; ++tj)
          #pragma unroll
          for (int r = 0; r < 4; ++r){
            int m = wm*32 + ti*16 + crow4 + r;
            int nn = wn*32 + tj*16 + ccol;
            gates[(size_t)(ng*64 + m)*NG6 + rg*64 + nn] = acc[ti][tj][r];
          }
    }
    target += 256;
    gridbar(bar, target);
    // ---- Phase B: epilogue ----
    int items = n * 4;
    for (int it = blockIdx.x; it < items; it += 256){
      int ns = it >> 2;
      int j = (it & 3)*256 + tid;
      int gid = order[loffv + ns];
      int b = node_b[gid];
      int el = node_l[gid], er = node_r[gid], xt = node_x[gid];
      float gg[6];
      #pragma unroll
      for (int q = 0; q < 6; ++q)
        gg[q] = bc[q*HH + j] + gates[(size_t)ns*NG6 + q*HH + j];
      float lc = (el < 0) ? 0.f : (el >= 10000 ? cs[(size_t)(b*LL + (el-10000))*HH + j]
                                               : nodeC[(size_t)el*HH + j]);
      float rc = (er < 0) ? 0.f : (er >= 10000 ? cs[(size_t)(b*LL + (er-10000))*HH + j]
                                               : nodeC[(size_t)er*HH + j]);
      float xc = cs[(size_t)(b*LL + xt)*HH + j];
      float c = sigf(gg[0])*tanhf(gg[4]) + sigf(gg[1])*lc + sigf(gg[2])*rc + sigf(gg[3])*xc;
      float h = sigf(gg[5])*tanhf(c);
      nodeH_bf[(size_t)gid*HH + j] = f2bf(h);
      nodeC[(size_t)gid*HH + j] = c;
      if (node_root[gid]){
        out[(size_t)b*HH + j] = h;
        out[(size_t)BB*HH + (size_t)b*HH + j] = c;
      }
    }
    if (lvl < nlev){
      target += 256;
      gridbar(bar, target);
    }
  }
}

// ---------------------------------------------------------------------------
extern "C" void kernel_launch(void* const* d_in, const int* in_sizes, int n_in,
                              void* d_out, int out_size, void* d_ws, size_t ws_size,
                              hipStream_t stream){
  const float* se  = (const float*)d_in[0];
  const float* gu  = (const float*)d_in[1];
  const float* Wih = (const float*)d_in[2];
  const float* Whh = (const float*)d_in[3];
  const float* bih = (const float*)d_in[4];
  const float* bhh = (const float*)d_in[5];
  const float* R1  = (const float*)d_in[6];
  const float* R2  = (const float*)d_in[7];
  const float* Wc  = (const float*)d_in[8];
  const float* bc  = (const float*)d_in[9];
  const int*   len = (const int*)d_in[10];
  float* out = (float*)d_out;                 // [2,16,1024] fp32

  float* ws = (float*)d_ws;
  size_t off = 0;
  float* R1t   = ws + off; off += (size_t)HH*RANKH;
  float* Gx    = ws + off; off += (size_t)BB*LL*NG4;     // [m][t][4096]
  float* Gxt   = ws + off; off += (size_t)BB*LL*NG4;     // [t][4096][m]
  float* hs    = ws + off; off += (size_t)BB*LL*HH;
  float* cs    = ws + off; off += (size_t)BB*LL*HH;
  float* nodeC = ws + off; off += (size_t)TOTN*HH;
  float* gates = ws + off; off += (size_t)MAXNPL*NG6;
  unsigned short* Wc_bf    = (unsigned short*)(ws + off); off += (size_t)NG6*K3H/2;
  unsigned short* hs_bf    = (unsigned short*)(ws + off); off += (size_t)BB*LL*HH/2;
  unsigned short* nodeH_bf = (unsigned short*)(ws + off); off += (size_t)TOTN*HH/2 + 512;
  unsigned short* zrow     = (unsigned short*)(ws + off); off += 512;  // 1024 zero bf16
  float* score = ws + off; off += 1024;
  float* snoi  = ws + off; off += 1024;
  unsigned* bar = (unsigned*)(ws + off); off += 64;
  int* ib = (int*)(ws + off);
  int* node_l    = ib; ib += 768;
  int* node_r    = ib; ib += 768;
  int* node_x    = ib; ib += 768;
  int* node_lvl  = ib; ib += 768;
  int* node_b    = ib; ib += 768;
  int* node_root = ib; ib += 768;
  int* level_count = ib; ib += 64;
  int* level_off   = ib; ib += 64;
  int* order       = ib; ib += 768;

  // 0. zero barrier counters + dummy zero row (ws poisoned every launch)
  k_init<<<1, 256, 0, stream>>>(bar, zrow);
  // 1. R1 transpose + Wc bf16 conversion
  k_transpose<<<dim3(32, 4), dim3(32, 8), 0, stream>>>(R1, R1t, RANKH, HH);
  k_cvt_bf16<<<(NG6*K3H)/1024, 256, 0, stream>>>(Wc, Wc_bf, NG6*K3H);
  // 2. input-side gate GEMM (+ both biases), then transpose for the scan
  k_gemm_gx<<<dim3(12, 64), 256, 0, stream>>>(se, Wih, bih, bhh, Gx, BB*LL, NG4, HH);
  k_gx_t<<<dim3(48, 16), 256, 0, stream>>>(Gx, Gxt);
  // 3. persistent recurrent LSTM scan (48 steps, fence-free LLC barriers)
  k_lstm_scan<<<256, 256, 0, stream>>>(Whh, Gxt, hs, cs, hs_bf, bar);
  // 4. per-position scores + gumbel noise (fp32)
  k_score<<<BB*LL, 128, 0, stream>>>(R1t, R2, hs, gu, score, snoi);
  // 5. tree structure
  k_build<<<1, 64, 0, stream>>>(score, snoi, len, node_l, node_r, node_x,
                                node_lvl, node_b, node_root,
                                level_count, level_off, order);
  // 6. persistent level-by-level nary composition
  k_tree<<<256, 256, 0, stream>>>(Wc_bf, hs_bf, nodeH_bf, zrow, bc, cs, nodeC,
                                  node_l, node_r, node_x, node_b, node_root,
                                  level_count, level_off, order,
                                  gates, out, bar + 8);
}

// Round 7
// 2072.661 us; speedup vs baseline: 2.0345x; 1.2040x over previous
//
#include <hip/hip_runtime.h>
#include <math.h>

#define BB 16
#define LL 48
#define HH 1024
#define NG4 4096      // 4*H
#define NG6 6144      // 6*H
#define K3H 3072      // 3*H
#define RANKH 128
#define MAXN 47       // max nodes per batch (len-1 <= 47)
#define TOTN (BB*MAXN)
#define MAXLVL 48
#define MAXNPL 384    // max nodes in one level

#define CH 20         // padded floats per 16-float k-chunk in scan LDS
#define HROW (64*CH)  // 1280 floats per m-row

typedef __attribute__((ext_vector_type(8))) short bf16x8;
typedef __attribute__((ext_vector_type(4))) float f32x4;

__device__ __forceinline__ float sigf(float x){ return 1.f/(1.f + expf(-x)); }

__device__ __forceinline__ unsigned short f2bf(float f){
  union { float f; unsigned u; } v; v.f = f;
  unsigned r = v.u + 0x7fff + ((v.u >> 16) & 1);
  return (unsigned short)(r >> 16);
}

// ---- LLC-coherent ops (device coherence point; bypass L1/L2, no allocate) ----
__device__ __forceinline__ void st_llc(float* p, float v){
  __hip_atomic_store(p, v, __ATOMIC_RELAXED, __HIP_MEMORY_SCOPE_AGENT);
}
__device__ __forceinline__ float ld_llc(const float* p){
  return __hip_atomic_load(p, __ATOMIC_RELAXED, __HIP_MEMORY_SCOPE_AGENT);
}
__device__ __forceinline__ f32x4 ld_llc4f(const float* p){
  f32x4 v;
  asm volatile("global_load_dwordx4 %0, %1, off sc0 sc1" : "=v"(v) : "v"(p));
  return v;
}
__device__ __forceinline__ void st_llc_u16(unsigned short* p, unsigned v){
  asm volatile("global_store_short %0, %1, off sc0 sc1" :: "v"(p), "v"(v) : "memory");
}
__device__ __forceinline__ void wait_vm0(){
  asm volatile("s_waitcnt vmcnt(0)" ::: "memory");
}

// Distributed-flag grid barrier: NO atomic RMW, NO writeback, NO invalidate.
// Each block stores flag[blockIdx]=p after vmcnt(0) (its LLC stores are ack'd);
// all 256 threads poll the 256 flags. Data crossing the barrier must use LLC
// ops (st_llc*) or be first-read-after-write (cached miss -> fresh LLC line).
// flags MUST be zeroed every launch (workspace re-poisoned to 0xAA).
__device__ __forceinline__ void flagbar(unsigned* flags, unsigned p, int* ldsok){
  wait_vm0();
  __syncthreads();
  if (threadIdx.x == 0)
    __hip_atomic_store(&flags[blockIdx.x], p, __ATOMIC_RELAXED, __HIP_MEMORY_SCOPE_AGENT);
  for (;;){
    unsigned f = __hip_atomic_load(&flags[threadIdx.x], __ATOMIC_RELAXED, __HIP_MEMORY_SCOPE_AGENT);
    int all4 = __all((int)(f >= p));
    if ((threadIdx.x & 63) == 0) ldsok[threadIdx.x >> 6] = all4;
    __syncthreads();
    if (ldsok[0] & ldsok[1] & ldsok[2] & ldsok[3]) break;
    __builtin_amdgcn_s_sleep(1);
    __syncthreads();
  }
}

// ---------------------------------------------------------------------------
// Zero flag arrays ([0..255]=scan, [256..511]=tree) + the zero dummy row.
__global__ __launch_bounds__(256) void k_init(unsigned* flags, unsigned short* zrow){
  int tid = threadIdx.x;
  flags[tid] = 0u;
  flags[256 + tid] = 0u;
  for (int i = tid; i < 1024; i += 256) zrow[i] = 0;
}

// ---------------------------------------------------------------------------
// fp32 -> bf16 (RNE), vectorized. n multiple of 1024.
__global__ __launch_bounds__(256) void k_cvt_bf16(const float* __restrict__ in,
    unsigned short* __restrict__ out, int n){
  int i = (blockIdx.x*256 + threadIdx.x)*4;
  if (i >= n) return;
  float4 v = *(const float4*)(in + i);
  ushort4 o;
  o.x = f2bf(v.x); o.y = f2bf(v.y); o.z = f2bf(v.z); o.w = f2bf(v.w);
  *(ushort4*)(out + i) = o;
}

// ---------------------------------------------------------------------------
// Generic 32x32 LDS-tiled transpose: out[C][R] = in[R][C]^T  (R1 only)
__global__ __launch_bounds__(256) void k_transpose(const float* __restrict__ in,
                                                   float* __restrict__ out, int R, int C){
  __shared__ float t[32][33];
  int bx = blockIdx.x*32, by = blockIdx.y*32;
  int x = threadIdx.x, y = threadIdx.y;   // block (32,8)
  #pragma unroll
  for (int i = 0; i < 32; i += 8){
    int r = by + y + i, c = bx + x;
    if (r < R && c < C) t[y+i][x] = in[(size_t)r*C + c];
  }
  __syncthreads();
  #pragma unroll
  for (int i = 0; i < 32; i += 8){
    int r = bx + y + i, c = by + x;       // out dims [C][R]
    if (r < C && c < R) out[(size_t)r*R + c] = t[x][y+i];
  }
}

// ---------------------------------------------------------------------------
// Gx[m][n] = sum_k se[m][k]*Wih[n][k] + bih[n] + bhh[n]   (fp32 — decision path)
__global__ __launch_bounds__(256) void k_gemm_gx(const float* __restrict__ A,
    const float* __restrict__ Bw, const float* __restrict__ bih,
    const float* __restrict__ bhh, float* __restrict__ Cout, int M, int N, int K){
  __shared__ float as[16][68];
  __shared__ float bs[16][68];
  int m0 = blockIdx.x*64, n0 = blockIdx.y*64;
  int tid = threadIdx.x;
  int mt = tid & 15, nt = tid >> 4;
  float acc[4][4] = {};
  for (int k0 = 0; k0 < K; k0 += 16){
    #pragma unroll
    for (int it = 0; it < 4; ++it){
      int idx = it*256 + tid;
      int kk = idx & 15, mm = idx >> 4;
      as[kk][mm] = A[(size_t)(m0+mm)*K + k0 + kk];
      bs[kk][mm] = Bw[(size_t)(n0+mm)*K + k0 + kk];
    }
    __syncthreads();
    #pragma unroll
    for (int kk = 0; kk < 16; ++kk){
      float a4[4], b4[4];
      #pragma unroll
      for (int i = 0; i < 4; ++i) a4[i] = as[kk][mt*4+i];
      #pragma unroll
      for (int i = 0; i < 4; ++i) b4[i] = bs[kk][nt*4+i];
      #pragma unroll
      for (int i = 0; i < 4; ++i)
        #pragma unroll
        for (int j2 = 0; j2 < 4; ++j2) acc[i][j2] += a4[i]*b4[j2];
    }
    __syncthreads();
  }
  #pragma unroll
  for (int i = 0; i < 4; ++i){
    int m = m0 + mt*4 + i;
    #pragma unroll
    for (int j2 = 0; j2 < 4; ++j2){
      int n = n0 + nt*4 + j2;
      Cout[(size_t)m*N + n] = acc[i][j2] + bih[n] + bhh[n];
    }
  }
}

// ---------------------------------------------------------------------------
// Gx [m][t][4096] -> Gxt [t][4096][m]  (for coalesced per-step gate reads)
__global__ __launch_bounds__(256) void k_gx_t(const float* __restrict__ Gx,
                                              float* __restrict__ Gxt){
  __shared__ float t2[16][257];
  int t = blockIdx.x;       // 48
  int rc = blockIdx.y;      // 16 chunks of 256 rows
  int tid = threadIdx.x;
  #pragma unroll
  for (int m = 0; m < 16; ++m)
    t2[m][tid] = Gx[((size_t)(m*48 + t))*4096 + rc*256 + tid];
  __syncthreads();
  int rl = tid >> 4, m = tid & 15;
  #pragma unroll
  for (int i = 0; i < 16; ++i){
    int r = rc*256 + i*16 + rl;
    Gxt[((size_t)t*4096 + r)*16 + m] = t2[m][i*16 + rl];
  }
}

// ---------------------------------------------------------------------------
// Persistent LSTM scan: 256 blocks x 256 threads, 1 block/CU.
// h exchanged through LLC; flag barrier (no RMW / wb / inv).
// Whh held in registers (w[4][16] per lane, lane=k-chunk of 16).
__global__ __launch_bounds__(256, 1) void k_lstm_scan(
    const float* __restrict__ Whh, const float* __restrict__ Gxt,
    float* __restrict__ hs, float* __restrict__ cs,
    unsigned short* __restrict__ hs_bf, unsigned* __restrict__ flags){
  __shared__ float smem[16*HROW];   // 80KB: h-stage; overlaid by reduce partials
  __shared__ float gbuf[4*64];
  __shared__ float cbuf[64];
  __shared__ int ldsok[4];
  int tid = threadIdx.x;
  int g = tid >> 6, kc = tid & 63;
  int j0 = blockIdx.x * 4;
  float w[4][16];
  #pragma unroll
  for (int jj = 0; jj < 4; ++jj){
    const float* src = Whh + (size_t)(g*1024 + j0 + jj)*1024 + kc*16;
    #pragma unroll
    for (int kk = 0; kk < 16; kk += 4){
      float4 v = *(const float4*)(src + kk);
      w[jj][kk]=v.x; w[jj][kk+1]=v.y; w[jj][kk+2]=v.z; w[jj][kk+3]=v.w;
    }
  }
  if (tid < 64) cbuf[tid] = 0.f;
  for (int t = 0; t < LL; ++t){
    float G = 0.f;
    if (t > 0){
      // batched LLC loads of h_{t-1}: 16 dwordx4 in flight, one vmcnt
      f32x4 hv[16];
      #pragma unroll
      for (int m = 0; m < 16; ++m)
        hv[m] = ld_llc4f(hs + ((size_t)(m*LL + t-1))*HH + (tid<<2));
      wait_vm0();
      #pragma unroll
      for (int m = 0; m < 16; ++m)
        *(f32x4*)&smem[m*HROW + (tid>>2)*CH + (tid&3)*4] = hv[m];
      __syncthreads();
      float acc[4][16];
      #pragma unroll 4
      for (int m = 0; m < 16; ++m){
        const float* hb = &smem[m*HROW + kc*CH];
        float4 h0 = *(const float4*)(hb);
        float4 h1 = *(const float4*)(hb+4);
        float4 h2 = *(const float4*)(hb+8);
        float4 h3 = *(const float4*)(hb+12);
        #pragma unroll
        for (int jj = 0; jj < 4; ++jj){
          float s = w[jj][0]*h0.x + w[jj][1]*h0.y + w[jj][2]*h0.z + w[jj][3]*h0.w
                  + w[jj][4]*h1.x + w[jj][5]*h1.y + w[jj][6]*h1.z + w[jj][7]*h1.w
                  + w[jj][8]*h2.x + w[jj][9]*h2.y + w[jj][10]*h2.z + w[jj][11]*h2.w
                  + w[jj][12]*h3.x + w[jj][13]*h3.y + w[jj][14]*h3.z + w[jj][15]*h3.w;
          acc[jj][m] = s;
        }
      }
      __syncthreads();   // hsm reads done; smem reused as reduce partials
      #pragma unroll
      for (int m = 0; m < 16; ++m){
        float4 v;
        v.x = acc[0][m]; v.y = acc[1][m]; v.z = acc[2][m]; v.w = acc[3][m];
        *(float4*)&smem[(size_t)(g*64 + kc)*68 + m*4] = v;
      }
      __syncthreads();
      {
        float s0=0.f,s1=0.f,s2=0.f,s3=0.f;
        #pragma unroll 4
        for (int l = 0; l < 64; l += 4){
          s0 += smem[(size_t)(g*64 + l  )*68 + kc];
          s1 += smem[(size_t)(g*64 + l+1)*68 + kc];
          s2 += smem[(size_t)(g*64 + l+2)*68 + kc];
          s3 += smem[(size_t)(g*64 + l+3)*68 + kc];
        }
        G = (s0+s1)+(s2+s3);
      }
    }
    gbuf[g*64 + kc] = G;
    __syncthreads();
    if (g == 0){
      int o = kc;               // o = m*4 + jj
      int jj = o & 3, m = o >> 2;
      size_t gxb = ((size_t)t*NG4 + j0 + jj)*16 + m;
      float gi = gbuf[0*64 + o] + Gxt[gxb + 0*16384];
      float gf = gbuf[1*64 + o] + Gxt[gxb + 1*16384];
      float gu = gbuf[2*64 + o] + Gxt[gxb + 2*16384];
      float go = gbuf[3*64 + o] + Gxt[gxb + 3*16384];
      float cp = cbuf[o];
      float c = sigf(gf)*cp + sigf(gi)*tanhf(gu);
      float h = sigf(go)*tanhf(c);
      cbuf[o] = c;
      size_t oidx = ((size_t)(m*LL + t))*HH + j0 + jj;
      st_llc(&hs[oidx], h);     // LLC write-through: visible without fences
      cs[oidx] = c;             // consumed after kernel boundary only
      hs_bf[oidx] = f2bf(h);    // consumed after kernel boundary only
    }
    if (t < LL-1)
      flagbar(flags, (unsigned)(t+1), ldsok);
  }
}

// ---------------------------------------------------------------------------
// Per-position rank-MLP score + gumbel noise (fp32 — decision path).
__global__ __launch_bounds__(128) void k_score(const float* __restrict__ R1t,
    const float* __restrict__ R2, const float* __restrict__ hs,
    const float* __restrict__ gumbel_u, float* __restrict__ score,
    float* __restrict__ snoisy){
  __shared__ float hsm[HH];
  __shared__ float red[128];
  int bt = blockIdx.x;
  int tid = threadIdx.x;
  for (int i = tid; i < HH; i += 128) hsm[i] = hs[(size_t)bt*HH + i];
  __syncthreads();
  float acc = 0.f;
  for (int k = 0; k < HH; ++k) acc += R1t[(size_t)k*RANKH + tid] * hsm[k];
  red[tid] = fmaxf(acc, 0.f) * R2[tid];
  __syncthreads();
  for (int s = 64; s > 0; s >>= 1){
    if (tid < s) red[tid] += red[tid+s];
    __syncthreads();
  }
  if (tid == 0){
    float s = red[0];
    float u = gumbel_u[bt];
    float noise = -logf(-logf(u));
    score[bt]  = s;
    snoisy[bt] = s + noise;
  }
}

// ---------------------------------------------------------------------------
// Build the tree structure for all batches. 1 block, 64 threads.
// level_count[0] <- number of levels (max height).
__global__ __launch_bounds__(64) void k_build(const float* __restrict__ score,
    const float* __restrict__ snoisy, const int* __restrict__ length,
    int* __restrict__ node_l, int* __restrict__ node_r, int* __restrict__ node_x,
    int* __restrict__ node_lvl, int* __restrict__ node_b, int* __restrict__ node_root,
    int* __restrict__ level_count, int* __restrict__ level_off, int* __restrict__ order){
  __shared__ float sc[BB*LL], sn[BB*LL];
  __shared__ int lcount[MAXLVL+1], lcur[MAXLVL+1], loff[MAXLVL+1];
  __shared__ int percnt[BB];
  int tid = threadIdx.x;
  for (int i = tid; i < BB*LL; i += 64){ sc[i] = score[i]; sn[i] = snoisy[i]; }
  for (int i = tid; i <= MAXLVL; i += 64){ lcount[i] = 0; lcur[i] = 0; }
  __syncthreads();
  if (tid < BB){
    int b = tid;
    int len = length[b];
    if (len > LL) len = LL;
    int qs[MAXN], qe[MAXN], qn[MAXN];
    int qh = 0, qt = 0, cnt = 0;
    int rootn = cnt++;
    qs[qt] = 0; qe[qt] = len; qn[qt] = rootn; qt++;
    while (qh < qt){
      int s0 = qs[qh], e0 = qe[qh], nid = qn[qh]; qh++;
      float best = sc[b*LL + s0]; int pos = s0;
      for (int t2 = s0+1; t2 < e0; ++t2){
        float v = sc[b*LL + t2];
        if (v > best){ best = v; pos = t2; }
      }
      float bestn = sn[b*LL + s0]; int js = s0;
      for (int t2 = s0+1; t2 < e0; ++t2){
        float v = sn[b*LL + t2];
        if (v > bestn){ bestn = v; js = t2; }
      }
      int gid = b*MAXN + nid;
      node_x[gid] = js;
      node_b[gid] = b;
      node_root[gid] = (nid == 0) ? 1 : 0;
      int ln = pos - s0, enc_l, enc_r;
      if (ln <= 0) enc_l = -1;
      else if (ln == 1) enc_l = 10000 + s0;
      else { int c2 = cnt++; enc_l = b*MAXN + c2; qs[qt]=s0; qe[qt]=pos; qn[qt]=c2; qt++; }
      int rn = e0 - (pos+1);
      if (rn <= 0) enc_r = -1;
      else if (rn == 1) enc_r = 10000 + (pos+1);
      else { int c2 = cnt++; enc_r = b*MAXN + c2; qs[qt]=pos+1; qe[qt]=e0; qn[qt]=c2; qt++; }
      node_l[gid] = enc_l; node_r[gid] = enc_r;
    }
    for (int i = cnt-1; i >= 0; --i){
      int gid = b*MAXN + i;
      int el = node_l[gid], er = node_r[gid];
      int llv = (el >= 0 && el < 10000) ? node_lvl[el] : 0;
      int rlv = (er >= 0 && er < 10000) ? node_lvl[er] : 0;
      node_lvl[gid] = 1 + (llv > rlv ? llv : rlv);
    }
    for (int i = 0; i < cnt; ++i) atomicAdd(&lcount[node_lvl[b*MAXN + i]], 1);
    percnt[b] = cnt;
  }
  __syncthreads();
  if (tid == 0){
    int off = 0, nlev = 0;
    for (int lv = 1; lv <= MAXLVL; ++lv){
      loff[lv] = off;
      level_off[lv] = off;
      level_count[lv] = lcount[lv];
      if (lcount[lv] > 0) nlev = lv;
      off += lcount[lv];
    }
    level_count[0] = nlev;
  }
  __syncthreads();
  if (tid < BB){
    int b = tid;
    int cnt = percnt[b];
    for (int i = 0; i < cnt; ++i){
      int gid = b*MAXN + i;
      int lv = node_lvl[gid];
      int p = atomicAdd(&lcur[lv], 1);
      order[loff[lv] + p] = gid;
    }
  }
}

// ---------------------------------------------------------------------------
// Persistent tree composition, flag barriers, NO wb/inv:
//  - gates: LLC stores (A) -> LLC loads (B)   [reused across levels: LLC ops
//    don't allocate L2 lines, so no staleness]
//  - nodeH_bf / nodeC: LLC stores (B) -> normal cached first-reads (A/B of the
//    parent level; each row written once, read once strictly later; consumer
//    L2 never held the line, so the miss fetches fresh LLC data)
//  - Wc_bf / hs_bf / order / node_*: read-only, stay warm in L2 across levels.
__global__ __launch_bounds__(256, 1) void k_tree(
    const unsigned short* __restrict__ Wc_bf,
    const unsigned short* __restrict__ hs_bf,
    unsigned short* __restrict__ nodeH_bf,
    const unsigned short* __restrict__ zrow,
    const float* __restrict__ bc, const float* __restrict__ cs,
    float* __restrict__ nodeC,
    const int* __restrict__ node_l, const int* __restrict__ node_r,
    const int* __restrict__ node_x, const int* __restrict__ node_b,
    const int* __restrict__ node_root, const int* __restrict__ level_count,
    const int* __restrict__ level_off, const int* __restrict__ order,
    float* __restrict__ gates, float* __restrict__ out,
    unsigned* __restrict__ flags){
  __shared__ int ldsok[4];
  int tid = threadIdx.x;
  int lane = tid & 63;
  int wave = tid >> 6;
  int wm = wave >> 1, wn = wave & 1;
  int fr = lane & 15, fk = (lane >> 4) * 8;
  int nlev = level_count[0];
  unsigned ph = 0;
  for (int lvl = 1; lvl <= nlev; ++lvl){
    int n = level_count[lvl];
    int loffv = level_off[lvl];
    int ntg = (n + 63) >> 6;
    int tiles = ntg * 96;
    // ---- Phase A: GEMM tiles (64 nodes x 64 Wc rows x K=3072) ----
    for (int tile = blockIdx.x; tile < tiles; tile += 256){
      int ng = tile / 96, rg = tile - ng*96;
      const unsigned short* pa[2][3];
      #pragma unroll
      for (int ti = 0; ti < 2; ++ti){
        int slot = ng*64 + wm*32 + ti*16 + fr;
        if (slot < n){
          int gid = order[loffv + slot];
          int b = node_b[gid];
          int el = node_l[gid], er = node_r[gid], xt = node_x[gid];
          pa[ti][0] = (el < 0) ? zrow : (el >= 10000 ? hs_bf + (size_t)(b*LL + (el-10000))*HH
                                                     : nodeH_bf + (size_t)el*HH);
          pa[ti][1] = (er < 0) ? zrow : (er >= 10000 ? hs_bf + (size_t)(b*LL + (er-10000))*HH
                                                     : nodeH_bf + (size_t)er*HH);
          pa[ti][2] = hs_bf + (size_t)(b*LL + xt)*HH;
        } else {
          pa[ti][0] = zrow; pa[ti][1] = zrow; pa[ti][2] = zrow;
        }
      }
      const unsigned short* pb0 = Wc_bf + (size_t)(rg*64 + wn*32 + fr)*K3H + fk;
      const unsigned short* pb1 = pb0 + (size_t)16*K3H;
      f32x4 acc[2][2] = {{{0.f,0.f,0.f,0.f},{0.f,0.f,0.f,0.f}},
                         {{0.f,0.f,0.f,0.f},{0.f,0.f,0.f,0.f}}};
      #pragma unroll
      for (int part = 0; part < 3; ++part){
        const unsigned short* a0p = pa[0][part] + fk;
        const unsigned short* a1p = pa[1][part] + fk;
        const unsigned short* b0p = pb0 + part*1024;
        const unsigned short* b1p = pb1 + part*1024;
        #pragma unroll 8
        for (int kcc = 0; kcc < 1024; kcc += 32){
          bf16x8 a0 = *(const bf16x8*)(a0p + kcc);
          bf16x8 a1 = *(const bf16x8*)(a1p + kcc);
          bf16x8 b0 = *(const bf16x8*)(b0p + kcc);
          bf16x8 b1 = *(const bf16x8*)(b1p + kcc);
          acc[0][0] = __builtin_amdgcn_mfma_f32_16x16x32_bf16(a0, b0, acc[0][0], 0, 0, 0);
          acc[0][1] = __builtin_amdgcn_mfma_f32_16x16x32_bf16(a0, b1, acc[0][1], 0, 0, 0);
          acc[1][0] = __builtin_amdgcn_mfma_f32_16x16x32_bf16(a1, b0, acc[1][0], 0, 0, 0);
          acc[1][1] = __builtin_amdgcn_mfma_f32_16x16x32_bf16(a1, b1, acc[1][1], 0, 0, 0);
        }
      }
      int crow4 = (lane >> 4)*4, ccol = lane & 15;
      #pragma unroll
      for (int ti = 0; ti < 2; ++ti)
        #pragma unroll
        for (int tj = 0; tj < 2; ++tj)
          #pragma unroll
          for (int r = 0; r < 4; ++r){
            int m = wm*32 + ti*16 + crow4 + r;
            int nn = wn*32 + tj*16 + ccol;
            st_llc(&gates[(size_t)(ng*64 + m)*NG6 + rg*64 + nn], acc[ti][tj][r]);
          }
    }
    ph++;
    flagbar(flags, ph, ldsok);
    // ---- Phase B: epilogue ----
    int items = n * 4;
    for (int it = blockIdx.x; it < items; it += 256){
      int ns = it >> 2;
      int j = (it & 3)*256 + tid;
      int gid = order[loffv + ns];
      int b = node_b[gid];
      int el = node_l[gid], er = node_r[gid], xt = node_x[gid];
      float gg[6];
      #pragma unroll
      for (int q = 0; q < 6; ++q)
        gg[q] = bc[q*HH + j] + ld_llc(&gates[(size_t)ns*NG6 + q*HH + j]);
      float lc = (el < 0) ? 0.f : (el >= 10000 ? cs[(size_t)(b*LL + (el-10000))*HH + j]
                                               : nodeC[(size_t)el*HH + j]);
      float rc = (er < 0) ? 0.f : (er >= 10000 ? cs[(size_t)(b*LL + (er-10000))*HH + j]
                                               : nodeC[(size_t)er*HH + j]);
      float xc = cs[(size_t)(b*LL + xt)*HH + j];
      float c = sigf(gg[0])*tanhf(gg[4]) + sigf(gg[1])*lc + sigf(gg[2])*rc + sigf(gg[3])*xc;
      float h = sigf(gg[5])*tanhf(c);
      st_llc_u16(&nodeH_bf[(size_t)gid*HH + j], (unsigned)f2bf(h));
      st_llc(&nodeC[(size_t)gid*HH + j], c);
      if (node_root[gid]){
        out[(size_t)b*HH + j] = h;
        out[(size_t)BB*HH + (size_t)b*HH + j] = c;
      }
    }
    if (lvl < nlev){
      ph++;
      flagbar(flags, ph, ldsok);
    }
  }
}

// ---------------------------------------------------------------------------
extern "C" void kernel_launch(void* const* d_in, const int* in_sizes, int n_in,
                              void* d_out, int out_size, void* d_ws, size_t ws_size,
                              hipStream_t stream){
  const float* se  = (const float*)d_in[0];
  const float* gu  = (const float*)d_in[1];
  const float* Wih = (const float*)d_in[2];
  const float* Whh = (const float*)d_in[3];
  const float* bih = (const float*)d_in[4];
  const float* bhh = (const float*)d_in[5];
  const float* R1  = (const float*)d_in[6];
  const float* R2  = (const float*)d_in[7];
  const float* Wc  = (const float*)d_in[8];
  const float* bc  = (const float*)d_in[9];
  const int*   len = (const int*)d_in[10];
  float* out = (float*)d_out;                 // [2,16,1024] fp32

  float* ws = (float*)d_ws;
  size_t off = 0;
  float* R1t   = ws + off; off += (size_t)HH*RANKH;
  float* Gx    = ws + off; off += (size_t)BB*LL*NG4;     // [m][t][4096]
  float* Gxt   = ws + off; off += (size_t)BB*LL*NG4;     // [t][4096][m]
  float* hs    = ws + off; off += (size_t)BB*LL*HH;
  float* cs    = ws + off; off += (size_t)BB*LL*HH;
  float* nodeC = ws + off; off += (size_t)TOTN*HH;
  float* gates = ws + off; off += (size_t)MAXNPL*NG6;
  unsigned short* Wc_bf    = (unsigned short*)(ws + off); off += (size_t)NG6*K3H/2;
  unsigned short* hs_bf    = (unsigned short*)(ws + off); off += (size_t)BB*LL*HH/2;
  unsigned short* nodeH_bf = (unsigned short*)(ws + off); off += (size_t)TOTN*HH/2 + 512;
  unsigned short* zrow     = (unsigned short*)(ws + off); off += 512;  // 1024 zero bf16
  float* score = ws + off; off += 1024;
  float* snoi  = ws + off; off += 1024;
  unsigned* flags = (unsigned*)(ws + off); off += 512;   // [0..255] scan, [256..511] tree
  int* ib = (int*)(ws + off);
  int* node_l    = ib; ib += 768;
  int* node_r    = ib; ib += 768;
  int* node_x    = ib; ib += 768;
  int* node_lvl  = ib; ib += 768;
  int* node_b    = ib; ib += 768;
  int* node_root = ib; ib += 768;
  int* level_count = ib; ib += 64;
  int* level_off   = ib; ib += 64;
  int* order       = ib; ib += 768;

  // 0. zero flag arrays + dummy zero row (ws poisoned every launch)
  k_init<<<1, 256, 0, stream>>>(flags, zrow);
  // 1. R1 transpose + Wc bf16 conversion
  k_transpose<<<dim3(32, 4), dim3(32, 8), 0, stream>>>(R1, R1t, RANKH, HH);
  k_cvt_bf16<<<(NG6*K3H)/1024, 256, 0, stream>>>(Wc, Wc_bf, NG6*K3H);
  // 2. input-side gate GEMM (+ both biases), then transpose for the scan
  k_gemm_gx<<<dim3(12, 64), 256, 0, stream>>>(se, Wih, bih, bhh, Gx, BB*LL, NG4, HH);
  k_gx_t<<<dim3(48, 16), 256, 0, stream>>>(Gx, Gxt);
  // 3. persistent recurrent LSTM scan (48 steps, flag barriers)
  k_lstm_scan<<<256, 256, 0, stream>>>(Whh, Gxt, hs, cs, hs_bf, flags);
  // 4. per-position scores + gumbel noise (fp32)
  k_score<<<BB*LL, 128, 0, stream>>>(R1t, R2, hs, gu, score, snoi);
  // 5. tree structure
  k_build<<<1, 64, 0, stream>>>(score, snoi, len, node_l, node_r, node_x,
                                node_lvl, node_b, node_root,
                                level_count, level_off, order);
  // 6. persistent level-by-level nary composition (flag barriers)
  k_tree<<<256, 256, 0, stream>>>(Wc_bf, hs_bf, nodeH_bf, zrow, bc, cs, nodeC,
                                  node_l, node_r, node_x, node_b, node_root,
                                  level_count, level_off, order,
                                  gates, out, flags + 256);
}